// Round 8
// baseline (178.579 us; speedup 1.0000x reference)
//
#include <hip/hip_runtime.h>

#define W 256
#define H 256
#define HW (W*H)
#define NB 12
#define ROWS 16
#define BPI (H/ROWS)            // 16 strips per image
#define NBLK (NB*BPI)           // 192 blocks (1/CU, co-resident via cooperative launch)
#define NTHREADS 1024           // 16 waves; wave = row, lane = 4-px chunk
#define NUM_ITER 20
#define NSUPER (NUM_ITER/2)     // 10 supersteps of 2 iterations
#define TVEPS 1e-8f
#define NPL 28
#define NFK 6
#define FLAG_MAGIC 0x5A170000

// plane indices (within a block's payload slot), "their" row coords of the PRODUCER:
// down payload (producer rows 14,15; consumer = block below, as its rows -2,-1):
//   0:p1x(15) 1:p2x(15) 2:p1y(14) 3:p2y(14) 4:p1y(15) 5:p2y(15) 6:u0(15) 7:u1(15)
// up payload (producer rows 0..3; consumer = block above, as its rows 16..19):
//   8:p1x(0) 9:p2x(0) 10:p1x(1) 11:p2x(1) 12:p1x(2) 13:p2x(2)
//   14:p1y(0) 15:p2y(0) 16:p1y(1) 17:p2y(1) 18:p1y(2) 19:p2y(2) 20:p1y(3) 21:p2y(3)
//   22:u0(0) 23:u1(0) 24:u0(1) 25:u1(1) 26:u0(2) 27:u1(2)
#define FK_U0 0
#define FK_U1 1
#define FK_U2 2
#define FK_U3 3
#define FK_D14 4
#define FK_D15 5

__device__ __forceinline__ float aload(const float* p) {
    return __hip_atomic_load(p, __ATOMIC_RELAXED, __HIP_MEMORY_SCOPE_AGENT);
}
__device__ __forceinline__ void astore(float* p, float v) {
    __hip_atomic_store(p, v, __ATOMIC_RELAXED, __HIP_MEMORY_SCOPE_AGENT);
}
__device__ __forceinline__ void waitflag(const int* f, int tgt) {
    while (__hip_atomic_load(f, __ATOMIC_RELAXED, __HIP_MEMORY_SCOPE_AGENT) != tgt)
        __builtin_amdgcn_s_sleep(1);
    asm volatile("" ::: "memory");
}
__device__ __forceinline__ void setflag(int* f, int tgt) {
    asm volatile("s_waitcnt vmcnt(0)" ::: "memory");
    __hip_atomic_store(f, tgt, __ATOMIC_RELAXED, __HIP_MEMORY_SCOPE_AGENT);
}
__device__ __forceinline__ float fastrcp(float x) { return __builtin_amdgcn_rcpf(x); }

#define LD4(dst, ptr) { const float4 _t = *reinterpret_cast<const float4*>(ptr); \
                        dst[0]=_t.x; dst[1]=_t.y; dst[2]=_t.z; dst[3]=_t.w; }
#define ST4(ptr, src) { float4 _t; _t.x=src[0]; _t.y=src[1]; _t.z=src[2]; _t.w=src[3]; \
                        *reinterpret_cast<float4*>(ptr) = _t; }
#define LDPAY(dst, pl) { _Pragma("unroll") for (int c = 0; c < 4; ++c) dst[c] = aload(hp + (pl)*W + x0 + c); }
#define STPAY(pl, src) { _Pragma("unroll") for (int c = 0; c < 4; ++c) astore(hw + (pl)*W + x0 + c, src[c]); }
#define CP4(dst, src)  { _Pragma("unroll") for (int c = 0; c < 4; ++c) dst[c] = src[c]; }

__global__ __launch_bounds__(NTHREADS, 1) void tvl1_ts2_kernel(
    const float* __restrict__ xin,
    const float* __restrict__ lam,
    const float* __restrict__ tau,
    const float* __restrict__ theta,
    const float* __restrict__ wxv,
    const float* __restrict__ wyv,
    float* __restrict__ uout,
    float* __restrict__ halo,
    int* __restrict__ flags)
{
    __shared__ float xu0[ROWS+3][W];   // u rows 0..18
    __shared__ float xu1[ROWS+3][W];
    __shared__ float xq1[ROWS+2][W];   // p1y rows 0..17
    __shared__ float xq2[ROWS+2][W];

    const int tid  = threadIdx.x;
    const int lane = tid & 63;
    const int wv   = tid >> 6;          // row within strip, 0..15
    const int x0   = lane << 2;
    const int b    = blockIdx.x;
    const int n    = b / BPI, bi = b % BPI;
    const int r0   = bi * ROWS;
    const int grow = r0 + wv;
    const bool notTop = (bi > 0), notBot = (bi < BPI-1);

    const float th0 = theta[0];
    const float tl  = th0 * lam[0];
    const float tt  = tau[0] / th0;
    const float wx0 = wxv[0], wx1 = wxv[1], wx2 = wxv[2];
    const float wy0 = wyv[0], wy1 = wyv[1], wy2 = wyv[2];

    const float* __restrict__ I0 = xin + (size_t)n * HW;
    const float* __restrict__ I1 = xin + (size_t)(NB + n) * HW;

    auto grad4 = [&](int row, float* rr, float* ggx, float* ggy) {
        #pragma unroll
        for (int c = 0; c < 4; ++c) {
            const int xc = x0 + c;
            const int idx = row * W + xc;
            const bool xm = xc > 0, xp = xc < W-1, ym = row > 0, yp = row < H-1;
            float a00=0.f,a01=0.f,a02=0.f,a10=0.f,a12=0.f,a20=0.f,a21=0.f,a22=0.f;
            if (ym) { a01=I1[idx-W]; if (xm) a00=I1[idx-W-1]; if (xp) a02=I1[idx-W+1]; }
            if (xm) a10=I1[idx-1];
            if (xp) a12=I1[idx+1];
            if (yp) { a21=I1[idx+W]; if (xm) a20=I1[idx+W-1]; if (xp) a22=I1[idx+W+1]; }
            ggx[c] = ((a02-a00) + 2.f*(a12-a10) + (a22-a20)) * (1.f/6.f);
            ggy[c] = ((a20-a00) + 2.f*(a21-a01) + (a22-a02)) * (1.f/6.f);
            rr[c]  = I1[idx] - I0[idx];
        }
    };

    float rho[4], gxr[4], gyr[4];
    grad4(grow, rho, gxr, gyr);
    float rhoH[4]={0,0,0,0}, gxH[4]={0,0,0,0}, gyH[4]={0,0,0,0};
    {
        const bool hg = (wv == 0 && notTop) || (wv >= 13 && notBot);
        const int hrow = (wv == 0) ? (r0 - 1) : (r0 + ROWS + (15 - wv)); // 15->16,14->17,13->18
        if (hg) grad4(hrow, rhoH, gxH, gyH);
    }

    for (int k = tid; k < (ROWS+3)*W; k += NTHREADS) { (&xu0[0][0])[k]=0.f; (&xu1[0][0])[k]=0.f; }
    for (int k = tid; k < (ROWS+2)*W; k += NTHREADS) { (&xq1[0][0])[k]=0.f; (&xq2[0][0])[k]=0.f; }
    float u0[4]={0,0,0,0}, u1[4]={0,0,0,0};
    float p1x[4]={0,0,0,0}, p1y[4]={0,0,0,0}, p2x[4]={0,0,0,0}, p2y[4]={0,0,0,0};
    __syncthreads();

    // u-step: uu += -f*g + th0*div(p); identical code for own and halo rows (bitwise match)
    auto ustepF = [&](const float* rr, const float* ggx, const float* ggy,
                      float* uu0, float* uu1,
                      const float* q1x, const float* q1ym, const float* q1yc, const float* q1yp,
                      const float* q2x, const float* q2ym, const float* q2yc, const float* q2yp) {
        float l1 = __shfl_up(q1x[3],1), l2 = __shfl_up(q2x[3],1);
        if (lane == 0) { l1 = 0.f; l2 = 0.f; }
        float r1 = __shfl_down(q1x[0],1), r2 = __shfl_down(q2x[0],1);
        if (lane == 63) { r1 = 0.f; r2 = 0.f; }
        const float x1m[4]={l1,q1x[0],q1x[1],q1x[2]}, x1p[4]={q1x[1],q1x[2],q1x[3],r1};
        const float x2m[4]={l2,q2x[0],q2x[1],q2x[2]}, x2p[4]={q2x[1],q2x[2],q2x[3],r2};
        #pragma unroll
        for (int c = 0; c < 4; ++c) {
            const float r  = rr[c] + ggx[c]*uu0[c] + ggy[c]*uu1[c];
            const float ng = ggx[c]*ggx[c] + ggy[c]*ggy[c] + TVEPS;
            const float f  = (fabsf(r) < tl*ng) ? (r * fastrcp(ng)) : copysignf(tl, r);
            const float d1 = wx0*x1m[c] + wx1*q1x[c] + wx2*x1p[c]
                           + wy0*q1ym[c] + wy1*q1yc[c] + wy2*q1yp[c];
            const float d2 = wx0*x2m[c] + wx1*q2x[c] + wx2*x2p[c]
                           + wy0*q2ym[c] + wy1*q2yc[c] + wy2*q2yp[c];
            uu0[c] = (uu0[c] - f*ggx[c]) + th0*d1;
            uu1[c] = (uu1[c] - f*ggy[c]) + th0*d2;
        }
    };
    auto pstepF = [&](const float* uc0, const float* uc1,
                      const float* uy0, const float* uy1,
                      float* q1x, float* q1y, float* q2x, float* q2y) {
        float ur0 = __shfl_down(uc0[0],1), ur1 = __shfl_down(uc1[0],1);
        if (lane == 63) { ur0 = 0.f; ur1 = 0.f; }
        #pragma unroll
        for (int c = 0; c < 4; ++c) {
            const float uxp0 = (c < 3) ? uc0[c+1] : ur0;
            const float uxp1 = (c < 3) ? uc1[c+1] : ur1;
            const float g1x = uxp0 - uc0[c], g1y = uy0[c] - uc0[c];
            const float g2x = uxp1 - uc1[c], g2y = uy1[c] - uc1[c];
            const float rc1 = fastrcp(1.f + tt * (fabsf(g1x) + fabsf(g1y)));
            const float rc2 = fastrcp(1.f + tt * (fabsf(g2x) + fabsf(g2y)));
            q1x[c] = (q1x[c] + tt*g1x) * rc1;  q1y[c] = (q1y[c] + tt*g1y) * rc1;
            q2x[c] = (q2x[c] + tt*g2x) * rc2;  q2y[c] = (q2y[c] + tt*g2y) * rc2;
        }
    };

    for (int S = 0; S < NSUPER; ++S) {
        const bool lastS = (S == NSUPER-1);
        float pay[10][4];
        #pragma unroll
        for (int i = 0; i < 10; ++i) { pay[i][0]=0.f; pay[i][1]=0.f; pay[i][2]=0.f; pay[i][3]=0.f; }
        // per-wave pay mapping:
        // wave0 : 0:p1x(-1) 1:p2x(-1) 2:p1y(-2) 3:p2y(-2) 4:p1y(-1) 5:p2y(-1) 6:u0(-1) 7:u1(-1)
        // wave15: 0:p1x(16) 1:p2x(16) 2:p1y(16) 3:p2y(16) 4:p1y(17) 5:p2y(17) 6:u0(16) 7:u1(16)
        // wave14: 0:p1x(17) 1:p2x(17) 2:p1y(16) 3:p2y(16) 4:p1y(17) 5:p2y(17) 6:u0(17) 7:u1(17) 8:p1y(18) 9:p2y(18)
        // wave13: 0:p1x(18) 1:p2x(18) 2:p1y(17) 3:p2y(17) 4:p1y(18) 5:p2y(18) 6:u0(18) 7:u1(18) 8:p1y(19) 9:p2y(19)

        auto ownU = [&]() {
            float pym1[4],pym2[4],pyp1[4],pyp2[4];
            if (wv > 0) { LD4(pym1,&xq1[wv-1][x0]); LD4(pym2,&xq2[wv-1][x0]); }
            else        { CP4(pym1,pay[4]); CP4(pym2,pay[5]); }
            if (wv < ROWS-1) { LD4(pyp1,&xq1[wv+1][x0]); LD4(pyp2,&xq2[wv+1][x0]); }
            else             { CP4(pyp1,pay[2]); CP4(pyp2,pay[3]); }
            ustepF(rho,gxr,gyr,u0,u1, p1x,pym1,p1y,pyp1, p2x,pym2,p2y,pyp2);
            ST4(&xu0[wv][x0],u0); ST4(&xu1[wv][x0],u1);
        };

        // ================= P1: u-step of iteration A =================
        if (wv != 0 && wv != ROWS-1) ownU();   // waves 1..14: no payload dependency
        if (S > 0) {
            int* fb = flags + (size_t)((S-1)&1)*NFK*NBLK;
            const int tgt = FLAG_MAGIC | (S-1);
            if (wv == 0 && notTop) {
                if (lane < 2) waitflag(&fb[(lane==0?FK_D14:FK_D15)*NBLK + (b-1)], tgt);
                const float* hp = halo + ((size_t)((S-1)&1)*NBLK + (b-1))*((size_t)NPL*W);
                LDPAY(pay[0],0); LDPAY(pay[1],1); LDPAY(pay[2],2); LDPAY(pay[3],3);
                LDPAY(pay[4],4); LDPAY(pay[5],5); LDPAY(pay[6],6); LDPAY(pay[7],7);
            } else if (wv == 15 && notBot) {
                if (lane < 2) waitflag(&fb[(lane==0?FK_U0:FK_U1)*NBLK + (b+1)], tgt);
                const float* hp = halo + ((size_t)((S-1)&1)*NBLK + (b+1))*((size_t)NPL*W);
                LDPAY(pay[0],8); LDPAY(pay[1],9); LDPAY(pay[2],14); LDPAY(pay[3],15);
                LDPAY(pay[4],16); LDPAY(pay[5],17); LDPAY(pay[6],22); LDPAY(pay[7],23);
            } else if (wv == 14 && notBot) {
                if (lane < 3) waitflag(&fb[(lane==0?FK_U0:(lane==1?FK_U1:FK_U2))*NBLK + (b+1)], tgt);
                const float* hp = halo + ((size_t)((S-1)&1)*NBLK + (b+1))*((size_t)NPL*W);
                LDPAY(pay[0],10); LDPAY(pay[1],11); LDPAY(pay[2],14); LDPAY(pay[3],15);
                LDPAY(pay[4],16); LDPAY(pay[5],17); LDPAY(pay[6],24); LDPAY(pay[7],25);
                LDPAY(pay[8],18); LDPAY(pay[9],19);
            } else if (wv == 13 && notBot) {
                if (lane < 3) waitflag(&fb[(lane==0?FK_U1:(lane==1?FK_U2:FK_U3))*NBLK + (b+1)], tgt);
                const float* hp = halo + ((size_t)((S-1)&1)*NBLK + (b+1))*((size_t)NPL*W);
                LDPAY(pay[0],12); LDPAY(pay[1],13); LDPAY(pay[2],16); LDPAY(pay[3],17);
                LDPAY(pay[4],18); LDPAY(pay[5],19); LDPAY(pay[6],26); LDPAY(pay[7],27);
                LDPAY(pay[8],20); LDPAY(pay[9],21);
            }
        }
        if (wv == 0 || wv == ROWS-1) ownU();
        // halo u1 recompute (bitwise-identical to neighbor's own rows)
        if (wv == 0 && notTop) {
            ustepF(rhoH,gxH,gyH, pay[6],pay[7],
                   pay[0], pay[2],pay[4],p1y,
                   pay[1], pay[3],pay[5],p2y);             // u1(-1), stays in regs
        } else if (wv == 15 && notBot) {
            ustepF(rhoH,gxH,gyH, pay[6],pay[7],
                   pay[0], p1y,pay[2],pay[4],
                   pay[1], p2y,pay[3],pay[5]);             // u1(16)
            ST4(&xu0[16][x0],pay[6]); ST4(&xu1[16][x0],pay[7]);
        } else if ((wv == 14 || wv == 13) && notBot) {
            ustepF(rhoH,gxH,gyH, pay[6],pay[7],
                   pay[0], pay[2],pay[4],pay[8],
                   pay[1], pay[3],pay[5],pay[9]);          // u1(17)/u1(18)
            const int hr = (wv == 14) ? 17 : 18;
            ST4(&xu0[hr][x0],pay[6]); ST4(&xu1[hr][x0],pay[7]);
        }
        __syncthreads();

        // ================= P2: p-step of iteration A =================
        {
            float uy0[4],uy1[4];
            LD4(uy0,&xu0[wv+1][x0]); LD4(uy1,&xu1[wv+1][x0]);   // xu[16]==0 at image bottom
            pstepF(u0,u1, uy0,uy1, p1x,p1y,p2x,p2y);
            ST4(&xq1[wv][x0],p1y); ST4(&xq2[wv][x0],p2y);
        }
        if (wv == 0 && notTop) {
            pstepF(pay[6],pay[7], u0,u1, pay[0],pay[4], pay[1],pay[5]);   // p(-1): y comps in pay[4],pay[5]
        } else if (wv == 15 && notBot) {
            float uy0[4],uy1[4]; LD4(uy0,&xu0[17][x0]); LD4(uy1,&xu1[17][x0]);
            pstepF(pay[6],pay[7], uy0,uy1, pay[0],pay[2], pay[1],pay[3]); // p(16)
            ST4(&xq1[16][x0],pay[2]); ST4(&xq2[16][x0],pay[3]);
        } else if (wv == 14 && notBot) {
            float uy0[4],uy1[4]; LD4(uy0,&xu0[18][x0]); LD4(uy1,&xu1[18][x0]);
            pstepF(pay[6],pay[7], uy0,uy1, pay[0],pay[4], pay[1],pay[5]); // p(17)
            ST4(&xq1[17][x0],pay[4]); ST4(&xq2[17][x0],pay[5]);
        }
        __syncthreads();

        // ================= P3: u-step of iteration B =================
        {
            float pym1[4],pym2[4],pyp1[4],pyp2[4];
            if (wv > 0) { LD4(pym1,&xq1[wv-1][x0]); LD4(pym2,&xq2[wv-1][x0]); }
            else        { CP4(pym1,pay[4]); CP4(pym2,pay[5]); }             // p1y(-1) new
            LD4(pyp1,&xq1[wv+1][x0]); LD4(pyp2,&xq2[wv+1][x0]);             // xq[16] valid/0
            ustepF(rho,gxr,gyr,u0,u1, p1x,pym1,p1y,pyp1, p2x,pym2,p2y,pyp2);
        }
        if (lastS) {
            float* __restrict__ o0 = uout + (size_t)(2*n)   * HW + (size_t)grow * W + x0;
            float* __restrict__ o1 = uout + (size_t)(2*n+1) * HW + (size_t)grow * W + x0;
            ST4(o0,u0); ST4(o1,u1);
            break;              // uniform across block
        }
        ST4(&xu0[wv][x0],u0); ST4(&xu1[wv][x0],u1);
        if (wv == 15 && notBot) {
            float yp1[4],yp2[4]; LD4(yp1,&xq1[17][x0]); LD4(yp2,&xq2[17][x0]);
            ustepF(rhoH,gxH,gyH, pay[6],pay[7],
                   pay[0], p1y,pay[2],yp1,
                   pay[1], p2y,pay[3],yp2);                // u2(16)
            ST4(&xu0[16][x0],pay[6]); ST4(&xu1[16][x0],pay[7]);
        }
        __syncthreads();

        // ================= P4: p-step of iteration B + publish =================
        {
            float uy0[4],uy1[4];
            LD4(uy0,&xu0[wv+1][x0]); LD4(uy1,&xu1[wv+1][x0]);   // xu[16]=u2(16) or 0
            pstepF(u0,u1, uy0,uy1, p1x,p1y,p2x,p2y);
            ST4(&xq1[wv][x0],p1y); ST4(&xq2[wv][x0],p2y);
        }
        {
            float* hw = halo + ((size_t)(S&1)*NBLK + b)*((size_t)NPL*W);
            int* fw = flags + (size_t)(S&1)*NFK*NBLK;
            const int ft = FLAG_MAGIC | S;
            if (notTop) {
                if (wv == 0)      { STPAY(8,p1x);  STPAY(9,p2x);  STPAY(14,p1y); STPAY(15,p2y);
                                    STPAY(22,u0);  STPAY(23,u1);  if (lane==0) setflag(&fw[FK_U0*NBLK+b],ft); }
                else if (wv == 1) { STPAY(10,p1x); STPAY(11,p2x); STPAY(16,p1y); STPAY(17,p2y);
                                    STPAY(24,u0);  STPAY(25,u1);  if (lane==0) setflag(&fw[FK_U1*NBLK+b],ft); }
                else if (wv == 2) { STPAY(12,p1x); STPAY(13,p2x); STPAY(18,p1y); STPAY(19,p2y);
                                    STPAY(26,u0);  STPAY(27,u1);  if (lane==0) setflag(&fw[FK_U2*NBLK+b],ft); }
                else if (wv == 3) { STPAY(20,p1y); STPAY(21,p2y); if (lane==0) setflag(&fw[FK_U3*NBLK+b],ft); }
            }
            if (notBot) {
                if (wv == 14)      { STPAY(2,p1y); STPAY(3,p2y); if (lane==0) setflag(&fw[FK_D14*NBLK+b],ft); }
                else if (wv == 15) { STPAY(0,p1x); STPAY(1,p2x); STPAY(4,p1y); STPAY(5,p2y);
                                     STPAY(6,u0);  STPAY(7,u1);  if (lane==0) setflag(&fw[FK_D15*NBLK+b],ft); }
            }
        }
        __syncthreads();
    }
}

// ---------------- fallback path (round-1, known good) ----------------

__global__ void precompute_kernel(const float* __restrict__ x,
                                  float* __restrict__ u,
                                  float* __restrict__ ws) {
    const int row = blockIdx.x;
    const int n = row / H, y = row % H;
    const int xx = threadIdx.x;
    const int idx = y * W + xx;
    const float* __restrict__ I0 = x + (size_t)n * HW;
    const float* __restrict__ I1 = x + (size_t)(NB + n) * HW;
    float* __restrict__ p1  = ws;
    float* __restrict__ p2  = ws + (size_t)2 * NB * HW;
    float* __restrict__ rho = ws + (size_t)4 * NB * HW;
    float* __restrict__ gxp = ws + (size_t)5 * NB * HW;
    float* __restrict__ gyp = ws + (size_t)6 * NB * HW;
    const float i1c = I1[idx];
    const bool xm = xx > 0, xp = xx < W - 1, ym = y > 0, yp = y < H - 1;
    float a00=0.f,a01=0.f,a02=0.f,a10=0.f,a12=0.f,a20=0.f,a21=0.f,a22=0.f;
    if (ym) { a01 = I1[idx-W]; if (xm) a00 = I1[idx-W-1]; if (xp) a02 = I1[idx-W+1]; }
    if (xm) a10 = I1[idx-1];
    if (xp) a12 = I1[idx+1];
    if (yp) { a21 = I1[idx+W]; if (xm) a20 = I1[idx+W-1]; if (xp) a22 = I1[idx+W+1]; }
    const float gxv = ((a02-a00) + 2.f*(a12-a10) + (a22-a20)) * (1.f/6.f);
    const float gyv = ((a20-a00) + 2.f*(a21-a01) + (a22-a02)) * (1.f/6.f);
    const size_t np = (size_t)n * HW;
    rho[np+idx] = i1c - I0[idx];
    gxp[np+idx] = gxv;
    gyp[np+idx] = gyv;
    u[(size_t)(2*n)*HW + idx] = 0.f;   u[(size_t)(2*n+1)*HW + idx] = 0.f;
    p1[(size_t)(2*n)*HW + idx] = 0.f;  p1[(size_t)(2*n+1)*HW + idx] = 0.f;
    p2[(size_t)(2*n)*HW + idx] = 0.f;  p2[(size_t)(2*n+1)*HW + idx] = 0.f;
}

__global__ void u_kernel(const float* __restrict__ ws,
                         float* __restrict__ u,
                         const float* __restrict__ lam,
                         const float* __restrict__ theta,
                         const float* __restrict__ wxv,
                         const float* __restrict__ wyv) {
    const int row = blockIdx.x;
    const int n = row / H, y = row % H;
    const int xx = threadIdx.x;
    const int idx = y * W + xx;
    const size_t np = (size_t)n * HW;
    const float* __restrict__ p1  = ws;
    const float* __restrict__ p2  = ws + (size_t)2 * NB * HW;
    const float* __restrict__ rho_c = ws + (size_t)4 * NB * HW;
    const float* __restrict__ gxp = ws + (size_t)5 * NB * HW;
    const float* __restrict__ gyp = ws + (size_t)6 * NB * HW;
    const float th0 = theta[0];
    const float tl = th0 * lam[0];
    const float wx0 = wxv[0], wx1 = wxv[1], wx2 = wxv[2];
    const float wy0 = wyv[0], wy1 = wyv[1], wy2 = wyv[2];
    const float gx = gxp[np+idx];
    const float gy = gyp[np+idx];
    float* __restrict__ u0p = u + (size_t)(2*n)*HW;
    float* __restrict__ u1p = u + (size_t)(2*n+1)*HW;
    const float u0 = u0p[idx], u1 = u1p[idx];
    const float rho = rho_c[np+idx] + gx*u0 + gy*u1;
    const float ng = gx*gx + gy*gy + TVEPS;
    const float th = tl * ng;
    float s0, s1;
    if (fabsf(rho) < th) { const float d = rho/ng; s0 = d*gx; s1 = d*gy; }
    else { const float sg = (rho > 0.f) ? 1.f : ((rho < 0.f) ? -1.f : 0.f);
           s0 = tl*gx*sg; s1 = tl*gy*sg; }
    const float v0 = u0 - s0, v1 = u1 - s1;
    const float* __restrict__ p1xp = p1 + (size_t)(2*n)*HW;
    const float* __restrict__ p1yp = p1 + (size_t)(2*n+1)*HW;
    const float* __restrict__ p2xp = p2 + (size_t)(2*n)*HW;
    const float* __restrict__ p2yp = p2 + (size_t)(2*n+1)*HW;
    float d1 = wx1*p1xp[idx] + wy1*p1yp[idx];
    float d2 = wx1*p2xp[idx] + wy1*p2yp[idx];
    if (xx > 0)     { d1 += wx0*p1xp[idx-1]; d2 += wx0*p2xp[idx-1]; }
    if (xx < W-1)   { d1 += wx2*p1xp[idx+1]; d2 += wx2*p2xp[idx+1]; }
    if (y > 0)      { d1 += wy0*p1yp[idx-W]; d2 += wy0*p2yp[idx-W]; }
    if (y < H-1)    { d1 += wy2*p1yp[idx+W]; d2 += wy2*p2yp[idx+W]; }
    u0p[idx] = v0 + th0*d1;
    u1p[idx] = v1 + th0*d2;
}

__global__ void p_kernel(const float* __restrict__ u,
                         float* __restrict__ ws,
                         const float* __restrict__ tau,
                         const float* __restrict__ theta) {
    const int row = blockIdx.x;
    const int n = row / H, y = row % H;
    const int xx = threadIdx.x;
    const int idx = y * W + xx;
    float* __restrict__ p1 = ws;
    float* __restrict__ p2 = ws + (size_t)2 * NB * HW;
    const float tt = tau[0] / theta[0];
    const float* __restrict__ u0p = u + (size_t)(2*n)*HW;
    const float* __restrict__ u1p = u + (size_t)(2*n+1)*HW;
    const float c0 = u0p[idx];
    const float g1x = ((xx < W-1) ? u0p[idx+1] : 0.f) - c0;
    const float g1y = ((y < H-1) ? u0p[idx+W] : 0.f) - c0;
    const float c1 = u1p[idx];
    const float g2x = ((xx < W-1) ? u1p[idx+1] : 0.f) - c1;
    const float g2y = ((y < H-1) ? u1p[idx+W] : 0.f) - c1;
    float* __restrict__ p1xp = p1 + (size_t)(2*n)*HW;
    float* __restrict__ p1yp = p1 + (size_t)(2*n+1)*HW;
    float* __restrict__ p2xp = p2 + (size_t)(2*n)*HW;
    float* __restrict__ p2yp = p2 + (size_t)(2*n+1)*HW;
    const float den1 = 1.f + tt * (fabsf(g1x) + fabsf(g1y));
    p1xp[idx] = (p1xp[idx] + tt*g1x) / den1;
    p1yp[idx] = (p1yp[idx] + tt*g1y) / den1;
    const float den2 = 1.f + tt * (fabsf(g2x) + fabsf(g2y));
    p2xp[idx] = (p2xp[idx] + tt*g2x) / den2;
    p2yp[idx] = (p2yp[idx] + tt*g2y) / den2;
}

extern "C" void kernel_launch(void* const* d_in, const int* in_sizes, int n_in,
                              void* d_out, int out_size, void* d_ws, size_t ws_size,
                              hipStream_t stream) {
    const float* x     = (const float*)d_in[0];
    const float* lam   = (const float*)d_in[1];
    const float* tau   = (const float*)d_in[2];
    const float* theta = (const float*)d_in[3];
    const float* wxv   = (const float*)d_in[4];
    const float* wyv   = (const float*)d_in[5];
    float* u = (float*)d_out;

    const size_t halo_floats = (size_t)2 * NBLK * NPL * W;
    const size_t need = halo_floats * sizeof(float) + (size_t)2 * NFK * NBLK * sizeof(int);

    if (ws_size >= need) {
        float* halo = (float*)d_ws;
        int* flags = (int*)((char*)d_ws + halo_floats * sizeof(float));
        void* args[] = { (void*)&x, (void*)&lam, (void*)&tau, (void*)&theta,
                         (void*)&wxv, (void*)&wyv, (void*)&u, (void*)&halo, (void*)&flags };
        hipLaunchCooperativeKernel((void*)tvl1_ts2_kernel, dim3(NBLK), dim3(NTHREADS),
                                   args, 0, stream);
    } else {
        float* ws = (float*)d_ws;
        const dim3 grid(NB * H);
        const dim3 block(W);
        precompute_kernel<<<grid, block, 0, stream>>>(x, u, ws);
        for (int it = 0; it < NUM_ITER; ++it) {
            u_kernel<<<grid, block, 0, stream>>>(ws, u, lam, theta, wxv, wyv);
            p_kernel<<<grid, block, 0, stream>>>(u, ws, tau, theta);
        }
    }
}

// Round 9
// 133.475 us; speedup vs baseline: 1.3379x; 1.3379x over previous
//
#include <hip/hip_runtime.h>

#define W 256
#define H 256
#define HW (W*H)
#define NB 12
#define ROWS 16
#define BPI (H/ROWS)            // 16 strips per image
#define NBLK (NB*BPI)           // 192 blocks (1/CU, co-resident via cooperative launch)
#define NTHREADS 1024           // 16 waves; wave = row, lane = 4-px chunk
#define NUM_ITER 20
#define TVEPS 1e-8f
#define NPLQ 8
#define FLAG_MAGIC 0x5A170000u

// d_ws: pay[2][NBLK][NPLQ][W] qwords; each qword = (tag<<32)|float_bits, tag=MAGIC|it.
// planes: 0:p1x(r0) 1:p1y(r0) 2:p2x(r0) 3:p2y(r0) 4:p1y(r1) 5:p2y(r1) 6:p1y(r15) 7:p2y(r15)
// Consumers poll data words directly (no separate flag, no producer drain):
//   wave0  <- planes 6,7 of b-1     (p rows -1)
//   wave15 <- planes 1,3 of b+1     (p row 16)
//   wave14 <- planes 0..5 of b+1    (halo row-16 recompute inputs)

__device__ __forceinline__ unsigned long long ald64(const unsigned long long* p) {
    return __hip_atomic_load(p, __ATOMIC_RELAXED, __HIP_MEMORY_SCOPE_AGENT);
}
__device__ __forceinline__ void pstore(unsigned long long* p, float v, unsigned tag) {
    const unsigned long long q = ((unsigned long long)tag << 32) | (unsigned long long)__float_as_uint(v);
    __hip_atomic_store(p, q, __ATOMIC_RELAXED, __HIP_MEMORY_SCOPE_AGENT);
}
__device__ __forceinline__ float fastrcp(float x) { return __builtin_amdgcn_rcpf(x); }

#define LD4(dst, ptr) { const float4 _t = *reinterpret_cast<const float4*>(ptr); \
                        dst[0]=_t.x; dst[1]=_t.y; dst[2]=_t.z; dst[3]=_t.w; }
#define ST4(ptr, src) { float4 _t; _t.x=src[0]; _t.y=src[1]; _t.z=src[2]; _t.w=src[3]; \
                        *reinterpret_cast<float4*>(ptr) = _t; }

__global__ __launch_bounds__(NTHREADS, 1) void tvl1_tag_kernel(
    const float* __restrict__ xin,
    const float* __restrict__ lam,
    const float* __restrict__ tau,
    const float* __restrict__ theta,
    const float* __restrict__ wxv,
    const float* __restrict__ wyv,
    float* __restrict__ uout,
    unsigned long long* __restrict__ pay)
{
    __shared__ float xu0[ROWS+1][W];   // u rows 0..16 (row16 maintained by wave 14)
    __shared__ float xu1[ROWS+1][W];
    __shared__ float xq1[ROWS][W];     // p1y rows 0..15
    __shared__ float xq2[ROWS][W];

    const int tid  = threadIdx.x;
    const int lane = tid & 63;
    const int wv   = tid >> 6;          // row within strip, 0..15
    const int x0   = lane << 2;
    const int b    = blockIdx.x;
    const int n    = b / BPI, bi = b % BPI;
    const int r0   = bi * ROWS;
    const int grow = r0 + wv;
    const bool notTop = (bi > 0), notBot = (bi < BPI-1);

    const float th0 = theta[0];
    const float tl  = th0 * lam[0];
    const float tt  = tau[0] / th0;
    const float wx0 = wxv[0], wx1 = wxv[1], wx2 = wxv[2];
    const float wy0 = wyv[0], wy1 = wyv[1], wy2 = wyv[2];

    const float* __restrict__ I0 = xin + (size_t)n * HW;
    const float* __restrict__ I1 = xin + (size_t)(NB + n) * HW;

    auto grad4 = [&](int row, float* rr, float* ggx, float* ggy) {
        #pragma unroll
        for (int c = 0; c < 4; ++c) {
            const int xc = x0 + c;
            const int idx = row * W + xc;
            const bool xm = xc > 0, xp = xc < W-1, ym = row > 0, yp = row < H-1;
            float a00=0.f,a01=0.f,a02=0.f,a10=0.f,a12=0.f,a20=0.f,a21=0.f,a22=0.f;
            if (ym) { a01=I1[idx-W]; if (xm) a00=I1[idx-W-1]; if (xp) a02=I1[idx-W+1]; }
            if (xm) a10=I1[idx-1];
            if (xp) a12=I1[idx+1];
            if (yp) { a21=I1[idx+W]; if (xm) a20=I1[idx+W-1]; if (xp) a22=I1[idx+W+1]; }
            ggx[c] = ((a02-a00) + 2.f*(a12-a10) + (a22-a20)) * (1.f/6.f);
            ggy[c] = ((a20-a00) + 2.f*(a21-a01) + (a22-a02)) * (1.f/6.f);
            rr[c]  = I1[idx] - I0[idx];
        }
    };

    float rho[4], gxr[4], gyr[4];
    grad4(grow, rho, gxr, gyr);
    float rho16[4]={0,0,0,0}, gx16[4]={0,0,0,0}, gy16[4]={0,0,0,0};
    if (wv == 14 && notBot) grad4(r0 + ROWS, rho16, gx16, gy16);

    for (int k = tid; k < (ROWS+1)*W; k += NTHREADS) { (&xu0[0][0])[k]=0.f; (&xu1[0][0])[k]=0.f; }
    for (int k = tid; k < ROWS*W;     k += NTHREADS) { (&xq1[0][0])[k]=0.f; (&xq2[0][0])[k]=0.f; }
    float u0[4]={0,0,0,0}, u1[4]={0,0,0,0};
    float p1x[4]={0,0,0,0}, p1y[4]={0,0,0,0}, p2x[4]={0,0,0,0}, p2y[4]={0,0,0,0};
    __syncthreads();

    auto ustep4 = [&](const float* rr, const float* ggx, const float* ggy,
                      const float* uu0, const float* uu1,
                      const float* x1m, const float* x1c, const float* x1p,
                      const float* q1m, const float* q1c, const float* q1p,
                      const float* x2m, const float* x2c, const float* x2p,
                      const float* q2m, const float* q2c, const float* q2p,
                      float* o0, float* o1) {
        #pragma unroll
        for (int c = 0; c < 4; ++c) {
            const float r  = rr[c] + ggx[c]*uu0[c] + ggy[c]*uu1[c];
            const float ng = ggx[c]*ggx[c] + ggy[c]*ggy[c] + TVEPS;
            const float f  = (fabsf(r) < tl*ng) ? (r * fastrcp(ng)) : copysignf(tl, r);
            const float d1 = wx0*x1m[c] + wx1*x1c[c] + wx2*x1p[c]
                           + wy0*q1m[c] + wy1*q1c[c] + wy2*q1p[c];
            const float d2 = wx0*x2m[c] + wx1*x2c[c] + wx2*x2p[c]
                           + wy0*q2m[c] + wy1*q2c[c] + wy2*q2p[c];
            o0[c] = (uu0[c] - f*ggx[c]) + th0*d1;
            o1[c] = (uu1[c] - f*ggy[c]) + th0*d2;
        }
    };

    for (int it = 0; it < NUM_ITER; ++it) {
        const bool last = (it == NUM_ITER-1);

        float hym1[4]={0,0,0,0}, hym2[4]={0,0,0,0};   // wave0: p1y/p2y row -1
        float hyp1[4]={0,0,0,0}, hyp2[4]={0,0,0,0};   // wave15: p1y/p2y row 16
        float c16x1[4]={0,0,0,0}, c16x2[4]={0,0,0,0}; // wave14: p1x/p2x row 16
        float c16c1[4]={0,0,0,0}, c16c2[4]={0,0,0,0}; // wave14: p1y/p2y row 16
        float c16p1[4]={0,0,0,0}, c16p2[4]={0,0,0,0}; // wave14: p1y/p2y row 17

        // ---- wave 0 / 15: poll prev-iter tagged payload, then own u-step ----
        if (it > 0) {
            const unsigned tg = FLAG_MAGIC | (unsigned)(it-1);
            if (wv == 0 && notTop) {
                const unsigned long long* hp = pay + ((size_t)((it-1)&1)*NBLK + (b-1))*((size_t)NPLQ*W);
                for (;;) {
                    unsigned long long q[8];
                    #pragma unroll
                    for (int c = 0; c < 4; ++c) {
                        q[c]   = ald64(hp + 6*W + x0 + c);
                        q[4+c] = ald64(hp + 7*W + x0 + c);
                    }
                    unsigned bad = 0;
                    #pragma unroll
                    for (int i = 0; i < 8; ++i) bad |= ((unsigned)(q[i] >> 32)) ^ tg;
                    if (bad == 0) {
                        #pragma unroll
                        for (int c = 0; c < 4; ++c) {
                            hym1[c] = __uint_as_float((unsigned)q[c]);
                            hym2[c] = __uint_as_float((unsigned)q[4+c]);
                        }
                        break;
                    }
                    __builtin_amdgcn_s_sleep(1);
                }
            }
            if (wv == 15 && notBot) {
                const unsigned long long* hp = pay + ((size_t)((it-1)&1)*NBLK + (b+1))*((size_t)NPLQ*W);
                for (;;) {
                    unsigned long long q[8];
                    #pragma unroll
                    for (int c = 0; c < 4; ++c) {
                        q[c]   = ald64(hp + 1*W + x0 + c);
                        q[4+c] = ald64(hp + 3*W + x0 + c);
                    }
                    unsigned bad = 0;
                    #pragma unroll
                    for (int i = 0; i < 8; ++i) bad |= ((unsigned)(q[i] >> 32)) ^ tg;
                    if (bad == 0) {
                        #pragma unroll
                        for (int c = 0; c < 4; ++c) {
                            hyp1[c] = __uint_as_float((unsigned)q[c]);
                            hyp2[c] = __uint_as_float((unsigned)q[4+c]);
                        }
                        break;
                    }
                    __builtin_amdgcn_s_sleep(1);
                }
            }
        }

        // ---- u-step (own row), all waves ----
        float pym1[4], pym2[4], pyp1[4], pyp2[4];
        if (wv > 0) { LD4(pym1, &xq1[wv-1][x0]); LD4(pym2, &xq2[wv-1][x0]); }
        else        { for (int c=0;c<4;++c){ pym1[c]=hym1[c]; pym2[c]=hym2[c]; } }
        if (wv < ROWS-1) { LD4(pyp1, &xq1[wv+1][x0]); LD4(pyp2, &xq2[wv+1][x0]); }
        else             { for (int c=0;c<4;++c){ pyp1[c]=hyp1[c]; pyp2[c]=hyp2[c]; } }

        float l1 = __shfl_up(p1x[3], 1);   float l2 = __shfl_up(p2x[3], 1);
        if (lane == 0) { l1 = 0.f; l2 = 0.f; }
        float r1 = __shfl_down(p1x[0], 1); float r2 = __shfl_down(p2x[0], 1);
        if (lane == 63) { r1 = 0.f; r2 = 0.f; }
        const float p1xm[4] = { l1, p1x[0], p1x[1], p1x[2] };
        const float p1xp[4] = { p1x[1], p1x[2], p1x[3], r1 };
        const float p2xm[4] = { l2, p2x[0], p2x[1], p2x[2] };
        const float p2xp[4] = { p2x[1], p2x[2], p2x[3], r2 };

        float nu0[4], nu1[4];
        ustep4(rho, gxr, gyr, u0, u1,
               p1xm, p1x, p1xp, pym1, p1y, pyp1,
               p2xm, p2x, p2xp, pym2, p2y, pyp2, nu0, nu1);
        #pragma unroll
        for (int c = 0; c < 4; ++c) { u0[c] = nu0[c]; u1[c] = nu1[c]; }

        if (last) {
            float* __restrict__ o0 = uout + (size_t)(2*n)   * HW + (size_t)grow * W + x0;
            float* __restrict__ o1 = uout + (size_t)(2*n+1) * HW + (size_t)grow * W + x0;
            ST4(o0, u0); ST4(o1, u1);
            break;              // uniform across block
        }

        ST4(&xu0[wv][x0], u0); ST4(&xu1[wv][x0], u1);

        // ---- wave 14: poll planes 0..5, recompute halo row-16 u (bitwise = neighbor row 0) ----
        if (wv == 14 && notBot) {
            const unsigned tg = FLAG_MAGIC | (unsigned)(it-1);
            if (it > 0) {
                const unsigned long long* hp = pay + ((size_t)((it-1)&1)*NBLK + (b+1))*((size_t)NPLQ*W);
                for (;;) {
                    unsigned long long q[24];
                    #pragma unroll
                    for (int pl = 0; pl < 6; ++pl) {
                        #pragma unroll
                        for (int c = 0; c < 4; ++c) q[pl*4+c] = ald64(hp + pl*W + x0 + c);
                    }
                    unsigned bad = 0;
                    #pragma unroll
                    for (int i = 0; i < 24; ++i) bad |= ((unsigned)(q[i] >> 32)) ^ tg;
                    if (bad == 0) {
                        #pragma unroll
                        for (int c = 0; c < 4; ++c) {
                            c16x1[c] = __uint_as_float((unsigned)q[0*4+c]);
                            c16c1[c] = __uint_as_float((unsigned)q[1*4+c]);
                            c16x2[c] = __uint_as_float((unsigned)q[2*4+c]);
                            c16c2[c] = __uint_as_float((unsigned)q[3*4+c]);
                            c16p1[c] = __uint_as_float((unsigned)q[4*4+c]);
                            c16p2[c] = __uint_as_float((unsigned)q[5*4+c]);
                        }
                        break;
                    }
                    __builtin_amdgcn_s_sleep(1);
                }
            }
            float q115[4], q215[4], u160[4], u161[4];
            LD4(q115, &xq1[ROWS-1][x0]); LD4(q215, &xq2[ROWS-1][x0]);  // prev-iter p1y/p2y(15)
            LD4(u160, &xu0[ROWS][x0]);   LD4(u161, &xu1[ROWS][x0]);    // self-maintained u(16)
            float hl1 = __shfl_up(c16x1[3], 1), hl2 = __shfl_up(c16x2[3], 1);
            if (lane == 0) { hl1 = 0.f; hl2 = 0.f; }
            float hr1 = __shfl_down(c16x1[0], 1), hr2 = __shfl_down(c16x2[0], 1);
            if (lane == 63) { hr1 = 0.f; hr2 = 0.f; }
            const float h1m[4] = { hl1, c16x1[0], c16x1[1], c16x1[2] };
            const float h1p[4] = { c16x1[1], c16x1[2], c16x1[3], hr1 };
            const float h2m[4] = { hl2, c16x2[0], c16x2[1], c16x2[2] };
            const float h2p[4] = { c16x2[1], c16x2[2], c16x2[3], hr2 };
            float n160[4], n161[4];
            ustep4(rho16, gx16, gy16, u160, u161,
                   h1m, c16x1, h1p, q115, c16c1, c16p1,
                   h2m, c16x2, h2p, q215, c16c2, c16p2, n160, n161);
            ST4(&xu0[ROWS][x0], n160); ST4(&xu1[ROWS][x0], n161);
        }
        __syncthreads();   // barrier 1: xu (incl. row 16) complete; prev-iter xq reads done

        // ---- p-step (own row) ----
        float uy0[4], uy1[4];
        if (grow == H-1) { for (int c=0;c<4;++c){ uy0[c]=0.f; uy1[c]=0.f; } }
        else             { LD4(uy0, &xu0[wv+1][x0]); LD4(uy1, &xu1[wv+1][x0]); }
        float ur0 = __shfl_down(u0[0], 1), ur1 = __shfl_down(u1[0], 1);
        if (lane == 63) { ur0 = 0.f; ur1 = 0.f; }
        #pragma unroll
        for (int c = 0; c < 4; ++c) {
            const float uxp0 = (c < 3) ? u0[c+1] : ur0;
            const float uxp1 = (c < 3) ? u1[c+1] : ur1;
            const float g1x = uxp0 - u0[c];
            const float g1y = uy0[c] - u0[c];
            const float g2x = uxp1 - u1[c];
            const float g2y = uy1[c] - u1[c];
            const float rc1 = fastrcp(1.f + tt * (fabsf(g1x) + fabsf(g1y)));
            const float rc2 = fastrcp(1.f + tt * (fabsf(g2x) + fabsf(g2y)));
            p1x[c] = (p1x[c] + tt*g1x) * rc1;
            p1y[c] = (p1y[c] + tt*g1y) * rc1;
            p2x[c] = (p2x[c] + tt*g2x) * rc2;
            p2y[c] = (p2y[c] + tt*g2y) * rc2;
        }
        ST4(&xq1[wv][x0], p1y); ST4(&xq2[wv][x0], p2y);

        // ---- publish tagged payload (no drain, no flag) ----
        {
            unsigned long long* hw = pay + ((size_t)(it&1)*NBLK + b)*((size_t)NPLQ*W);
            const unsigned tg = FLAG_MAGIC | (unsigned)it;
            if (wv == 0 && notTop) {
                #pragma unroll
                for (int c = 0; c < 4; ++c) {
                    pstore(hw + 0*W + x0 + c, p1x[c], tg);
                    pstore(hw + 1*W + x0 + c, p1y[c], tg);
                    pstore(hw + 2*W + x0 + c, p2x[c], tg);
                    pstore(hw + 3*W + x0 + c, p2y[c], tg);
                }
            } else if (wv == 1 && notTop) {
                #pragma unroll
                for (int c = 0; c < 4; ++c) {
                    pstore(hw + 4*W + x0 + c, p1y[c], tg);
                    pstore(hw + 5*W + x0 + c, p2y[c], tg);
                }
            } else if (wv == ROWS-1 && notBot) {
                #pragma unroll
                for (int c = 0; c < 4; ++c) {
                    pstore(hw + 6*W + x0 + c, p1y[c], tg);
                    pstore(hw + 7*W + x0 + c, p2y[c], tg);
                }
            }
        }
        __syncthreads();   // barrier 2: xq writes visible for next iter's u-step
    }
}

// ---------------- fallback path (round-1, known good) ----------------

__global__ void precompute_kernel(const float* __restrict__ x,
                                  float* __restrict__ u,
                                  float* __restrict__ ws) {
    const int row = blockIdx.x;
    const int n = row / H, y = row % H;
    const int xx = threadIdx.x;
    const int idx = y * W + xx;
    const float* __restrict__ I0 = x + (size_t)n * HW;
    const float* __restrict__ I1 = x + (size_t)(NB + n) * HW;
    float* __restrict__ p1  = ws;
    float* __restrict__ p2  = ws + (size_t)2 * NB * HW;
    float* __restrict__ rho = ws + (size_t)4 * NB * HW;
    float* __restrict__ gxp = ws + (size_t)5 * NB * HW;
    float* __restrict__ gyp = ws + (size_t)6 * NB * HW;
    const float i1c = I1[idx];
    const bool xm = xx > 0, xp = xx < W - 1, ym = y > 0, yp = y < H - 1;
    float a00=0.f,a01=0.f,a02=0.f,a10=0.f,a12=0.f,a20=0.f,a21=0.f,a22=0.f;
    if (ym) { a01 = I1[idx-W]; if (xm) a00 = I1[idx-W-1]; if (xp) a02 = I1[idx-W+1]; }
    if (xm) a10 = I1[idx-1];
    if (xp) a12 = I1[idx+1];
    if (yp) { a21 = I1[idx+W]; if (xm) a20 = I1[idx+W-1]; if (xp) a22 = I1[idx+W+1]; }
    const float gxv = ((a02-a00) + 2.f*(a12-a10) + (a22-a20)) * (1.f/6.f);
    const float gyv = ((a20-a00) + 2.f*(a21-a01) + (a22-a02)) * (1.f/6.f);
    const size_t np = (size_t)n * HW;
    rho[np+idx] = i1c - I0[idx];
    gxp[np+idx] = gxv;
    gyp[np+idx] = gyv;
    u[(size_t)(2*n)*HW + idx] = 0.f;   u[(size_t)(2*n+1)*HW + idx] = 0.f;
    p1[(size_t)(2*n)*HW + idx] = 0.f;  p1[(size_t)(2*n+1)*HW + idx] = 0.f;
    p2[(size_t)(2*n)*HW + idx] = 0.f;  p2[(size_t)(2*n+1)*HW + idx] = 0.f;
}

__global__ void u_kernel(const float* __restrict__ ws,
                         float* __restrict__ u,
                         const float* __restrict__ lam,
                         const float* __restrict__ theta,
                         const float* __restrict__ wxv,
                         const float* __restrict__ wyv) {
    const int row = blockIdx.x;
    const int n = row / H, y = row % H;
    const int xx = threadIdx.x;
    const int idx = y * W + xx;
    const size_t np = (size_t)n * HW;
    const float* __restrict__ p1  = ws;
    const float* __restrict__ p2  = ws + (size_t)2 * NB * HW;
    const float* __restrict__ rho_c = ws + (size_t)4 * NB * HW;
    const float* __restrict__ gxp = ws + (size_t)5 * NB * HW;
    const float* __restrict__ gyp = ws + (size_t)6 * NB * HW;
    const float th0 = theta[0];
    const float tl = th0 * lam[0];
    const float wx0 = wxv[0], wx1 = wxv[1], wx2 = wxv[2];
    const float wy0 = wyv[0], wy1 = wyv[1], wy2 = wyv[2];
    const float gx = gxp[np+idx];
    const float gy = gyp[np+idx];
    float* __restrict__ u0p = u + (size_t)(2*n)*HW;
    float* __restrict__ u1p = u + (size_t)(2*n+1)*HW;
    const float u0 = u0p[idx], u1 = u1p[idx];
    const float rho = rho_c[np+idx] + gx*u0 + gy*u1;
    const float ng = gx*gx + gy*gy + TVEPS;
    const float th = tl * ng;
    float s0, s1;
    if (fabsf(rho) < th) { const float d = rho/ng; s0 = d*gx; s1 = d*gy; }
    else { const float sg = (rho > 0.f) ? 1.f : ((rho < 0.f) ? -1.f : 0.f);
           s0 = tl*gx*sg; s1 = tl*gy*sg; }
    const float v0 = u0 - s0, v1 = u1 - s1;
    const float* __restrict__ p1xp = p1 + (size_t)(2*n)*HW;
    const float* __restrict__ p1yp = p1 + (size_t)(2*n+1)*HW;
    const float* __restrict__ p2xp = p2 + (size_t)(2*n)*HW;
    const float* __restrict__ p2yp = p2 + (size_t)(2*n+1)*HW;
    float d1 = wx1*p1xp[idx] + wy1*p1yp[idx];
    float d2 = wx1*p2xp[idx] + wy1*p2yp[idx];
    if (xx > 0)     { d1 += wx0*p1xp[idx-1]; d2 += wx0*p2xp[idx-1]; }
    if (xx < W-1)   { d1 += wx2*p1xp[idx+1]; d2 += wx2*p2xp[idx+1]; }
    if (y > 0)      { d1 += wy0*p1yp[idx-W]; d2 += wy0*p2yp[idx-W]; }
    if (y < H-1)    { d1 += wy2*p1yp[idx+W]; d2 += wy2*p2yp[idx+W]; }
    u0p[idx] = v0 + th0*d1;
    u1p[idx] = v1 + th0*d2;
}

__global__ void p_kernel(const float* __restrict__ u,
                         float* __restrict__ ws,
                         const float* __restrict__ tau,
                         const float* __restrict__ theta) {
    const int row = blockIdx.x;
    const int n = row / H, y = row % H;
    const int xx = threadIdx.x;
    const int idx = y * W + xx;
    float* __restrict__ p1 = ws;
    float* __restrict__ p2 = ws + (size_t)2 * NB * HW;
    const float tt = tau[0] / theta[0];
    const float* __restrict__ u0p = u + (size_t)(2*n)*HW;
    const float* __restrict__ u1p = u + (size_t)(2*n+1)*HW;
    const float c0 = u0p[idx];
    const float g1x = ((xx < W-1) ? u0p[idx+1] : 0.f) - c0;
    const float g1y = ((y < H-1) ? u0p[idx+W] : 0.f) - c0;
    const float c1 = u1p[idx];
    const float g2x = ((xx < W-1) ? u1p[idx+1] : 0.f) - c1;
    const float g2y = ((y < H-1) ? u1p[idx+W] : 0.f) - c1;
    float* __restrict__ p1xp = p1 + (size_t)(2*n)*HW;
    float* __restrict__ p1yp = p1 + (size_t)(2*n+1)*HW;
    float* __restrict__ p2xp = p2 + (size_t)(2*n)*HW;
    float* __restrict__ p2yp = p2 + (size_t)(2*n+1)*HW;
    const float den1 = 1.f + tt * (fabsf(g1x) + fabsf(g1y));
    p1xp[idx] = (p1xp[idx] + tt*g1x) / den1;
    p1yp[idx] = (p1yp[idx] + tt*g1y) / den1;
    const float den2 = 1.f + tt * (fabsf(g2x) + fabsf(g2y));
    p2xp[idx] = (p2xp[idx] + tt*g2x) / den2;
    p2yp[idx] = (p2yp[idx] + tt*g2y) / den2;
}

extern "C" void kernel_launch(void* const* d_in, const int* in_sizes, int n_in,
                              void* d_out, int out_size, void* d_ws, size_t ws_size,
                              hipStream_t stream) {
    const float* x     = (const float*)d_in[0];
    const float* lam   = (const float*)d_in[1];
    const float* tau   = (const float*)d_in[2];
    const float* theta = (const float*)d_in[3];
    const float* wxv   = (const float*)d_in[4];
    const float* wyv   = (const float*)d_in[5];
    float* u = (float*)d_out;

    const size_t need = (size_t)2 * NBLK * NPLQ * W * sizeof(unsigned long long);

    if (ws_size >= need) {
        unsigned long long* pay = (unsigned long long*)d_ws;
        void* args[] = { (void*)&x, (void*)&lam, (void*)&tau, (void*)&theta,
                         (void*)&wxv, (void*)&wyv, (void*)&u, (void*)&pay };
        hipLaunchCooperativeKernel((void*)tvl1_tag_kernel, dim3(NBLK), dim3(NTHREADS),
                                   args, 0, stream);
    } else {
        float* ws = (float*)d_ws;
        const dim3 grid(NB * H);
        const dim3 block(W);
        precompute_kernel<<<grid, block, 0, stream>>>(x, u, ws);
        for (int it = 0; it < NUM_ITER; ++it) {
            u_kernel<<<grid, block, 0, stream>>>(ws, u, lam, theta, wxv, wyv);
            p_kernel<<<grid, block, 0, stream>>>(u, ws, tau, theta);
        }
    }
}

// Round 10
// 123.305 us; speedup vs baseline: 1.4483x; 1.0825x over previous
//
#include <hip/hip_runtime.h>

#define W 256
#define H 256
#define HW (W*H)
#define NB 12
#define ROWS 16
#define BPI (H/ROWS)            // 16 strips per image
#define NBLK (NB*BPI)           // 192 blocks (1/CU, co-resident via cooperative launch)
#define NTHREADS 1024           // 16 waves; wave = row, lane = 4-px chunk
#define NUM_ITER 20
#define TVEPS 1e-8f
#define HPLANES 8
#define FLAG_MAGIC 0x5A170000

// d_ws layout: halo[NUM_ITER-1][NBLK][HPLANES][W] floats, then flags[NUM_ITER-1][3][NBLK].
// planes: 0:p1x(r0) 1:p1y(r0) 2:p2x(r0) 3:p2y(r0) 4:p1y(r1) 5:p2y(r1) 6:p1y(r15) 7:p2y(r15)
// flags : 0=A (wave0, planes0-3) 1=B (wave1, planes4-5) 2=C (wave15, planes6-7)
// One IC handshake per iteration; consumers DEFER the halo term of the u-step so the
// poll happens after the bulk of phase-A compute (max overlap with the round trip).

__device__ __forceinline__ float aload(const float* p) {
    return __hip_atomic_load(p, __ATOMIC_RELAXED, __HIP_MEMORY_SCOPE_AGENT);
}
__device__ __forceinline__ void astore(float* p, float v) {
    __hip_atomic_store(p, v, __ATOMIC_RELAXED, __HIP_MEMORY_SCOPE_AGENT);
}
__device__ __forceinline__ void waitflag(const int* f, int tgt) {
    while (__hip_atomic_load(f, __ATOMIC_RELAXED, __HIP_MEMORY_SCOPE_AGENT) != tgt)
        __builtin_amdgcn_s_sleep(1);
    asm volatile("" ::: "memory");
}
__device__ __forceinline__ void setflag(int* f, int tgt) {
    asm volatile("s_waitcnt vmcnt(0)" ::: "memory");
    __hip_atomic_store(f, tgt, __ATOMIC_RELAXED, __HIP_MEMORY_SCOPE_AGENT);
}
__device__ __forceinline__ float fastrcp(float x) { return __builtin_amdgcn_rcpf(x); }

#define LD4(dst, ptr) { const float4 _t = *reinterpret_cast<const float4*>(ptr); \
                        dst[0]=_t.x; dst[1]=_t.y; dst[2]=_t.z; dst[3]=_t.w; }
#define ST4(ptr, src) { float4 _t; _t.x=src[0]; _t.y=src[1]; _t.z=src[2]; _t.w=src[3]; \
                        *reinterpret_cast<float4*>(ptr) = _t; }
#define CP4(dst, src) { _Pragma("unroll") for (int c = 0; c < 4; ++c) dst[c] = src[c]; }

__global__ __launch_bounds__(NTHREADS, 1) void tvl1_dfr_kernel(
    const float* __restrict__ xin,
    const float* __restrict__ lam,
    const float* __restrict__ tau,
    const float* __restrict__ theta,
    const float* __restrict__ wxv,
    const float* __restrict__ wyv,
    float* __restrict__ uout,
    float* __restrict__ halo,
    int* __restrict__ flags)
{
    __shared__ float xu0[ROWS][W];     // new u rows 0..15 (row 0 unused by readers)
    __shared__ float xu1[ROWS][W];
    __shared__ float xq1[ROWS][W];     // p1y rows 0..15 (prev iter during phase A)
    __shared__ float xq2[ROWS][W];

    const int tid  = threadIdx.x;
    const int lane = tid & 63;
    const int wv   = tid >> 6;          // row within strip, 0..15
    const int x0   = lane << 2;
    const int b    = blockIdx.x;
    const int n    = b / BPI, bi = b % BPI;
    const int r0   = bi * ROWS;
    const int grow = r0 + wv;
    const bool notTop = (bi > 0), notBot = (bi < BPI-1);

    const float th0 = theta[0];
    const float tl  = th0 * lam[0];
    const float tt  = tau[0] / th0;
    const float wx0 = wxv[0], wx1 = wxv[1], wx2 = wxv[2];
    const float wy0 = wyv[0], wy1 = wyv[1], wy2 = wyv[2];

    const float* __restrict__ I0 = xin + (size_t)n * HW;
    const float* __restrict__ I1 = xin + (size_t)(NB + n) * HW;

    auto grad4 = [&](int row, float* rr, float* ggx, float* ggy) {
        #pragma unroll
        for (int c = 0; c < 4; ++c) {
            const int xc = x0 + c;
            const int idx = row * W + xc;
            const bool xm = xc > 0, xp = xc < W-1, ym = row > 0, yp = row < H-1;
            float a00=0.f,a01=0.f,a02=0.f,a10=0.f,a12=0.f,a20=0.f,a21=0.f,a22=0.f;
            if (ym) { a01=I1[idx-W]; if (xm) a00=I1[idx-W-1]; if (xp) a02=I1[idx-W+1]; }
            if (xm) a10=I1[idx-1];
            if (xp) a12=I1[idx+1];
            if (yp) { a21=I1[idx+W]; if (xm) a20=I1[idx+W-1]; if (xp) a22=I1[idx+W+1]; }
            ggx[c] = ((a02-a00) + 2.f*(a12-a10) + (a22-a20)) * (1.f/6.f);
            ggy[c] = ((a20-a00) + 2.f*(a21-a01) + (a22-a02)) * (1.f/6.f);
            rr[c]  = I1[idx] - I0[idx];
        }
    };

    float rho[4], gxr[4], gyr[4];
    grad4(grow, rho, gxr, gyr);
    float rho16[4]={0,0,0,0}, gx16[4]={0,0,0,0}, gy16[4]={0,0,0,0};
    float u16_0[4]={0,0,0,0}, u16_1[4]={0,0,0,0};   // wave15: persistent u(16) mirror
    if (wv == 15 && notBot) grad4(r0 + ROWS, rho16, gx16, gy16);

    for (int k = tid; k < ROWS*W; k += NTHREADS) {
        (&xu0[0][0])[k]=0.f; (&xu1[0][0])[k]=0.f;
        (&xq1[0][0])[k]=0.f; (&xq2[0][0])[k]=0.f;
    }
    float u0[4]={0,0,0,0}, u1[4]={0,0,0,0};
    float p1x[4]={0,0,0,0}, p1y[4]={0,0,0,0}, p2x[4]={0,0,0,0}, p2y[4]={0,0,0,0};
    __syncthreads();

    // split-order u-step, ym term DEFERRED (caller adds th0*(wy0*q1m) afterwards)
    auto ustep_dym = [&](const float* rr, const float* ggx, const float* ggy,
                         const float* uu0, const float* uu1,
                         const float* x1, const float* q1c, const float* q1p,
                         const float* x2, const float* q2c, const float* q2p,
                         float* o0, float* o1) {
        float l1 = __shfl_up(x1[3],1), l2 = __shfl_up(x2[3],1);
        if (lane == 0) { l1 = 0.f; l2 = 0.f; }
        float r1 = __shfl_down(x1[0],1), r2 = __shfl_down(x2[0],1);
        if (lane == 63) { r1 = 0.f; r2 = 0.f; }
        const float x1m[4]={l1,x1[0],x1[1],x1[2]}, x1p[4]={x1[1],x1[2],x1[3],r1};
        const float x2m[4]={l2,x2[0],x2[1],x2[2]}, x2p[4]={x2[1],x2[2],x2[3],r2};
        #pragma unroll
        for (int c = 0; c < 4; ++c) {
            const float r  = rr[c] + ggx[c]*uu0[c] + ggy[c]*uu1[c];
            const float ng = ggx[c]*ggx[c] + ggy[c]*ggy[c] + TVEPS;
            const float f  = (fabsf(r) < tl*ng) ? (r * fastrcp(ng)) : copysignf(tl, r);
            const float d1 = wx0*x1m[c] + wx1*x1[c] + wx2*x1p[c] + wy1*q1c[c] + wy2*q1p[c];
            const float d2 = wx0*x2m[c] + wx1*x2[c] + wx2*x2p[c] + wy1*q2c[c] + wy2*q2p[c];
            o0[c] = (uu0[c] - f*ggx[c]) + th0*d1;
            o1[c] = (uu1[c] - f*ggy[c]) + th0*d2;
        }
    };
    // split-order u-step, yp term DEFERRED (caller adds th0*(wy2*q1p) afterwards)
    auto ustep_dyp = [&](const float* rr, const float* ggx, const float* ggy,
                         const float* uu0, const float* uu1,
                         const float* x1, const float* q1m, const float* q1c,
                         const float* x2, const float* q2m, const float* q2c,
                         float* o0, float* o1) {
        float l1 = __shfl_up(x1[3],1), l2 = __shfl_up(x2[3],1);
        if (lane == 0) { l1 = 0.f; l2 = 0.f; }
        float r1 = __shfl_down(x1[0],1), r2 = __shfl_down(x2[0],1);
        if (lane == 63) { r1 = 0.f; r2 = 0.f; }
        const float x1m[4]={l1,x1[0],x1[1],x1[2]}, x1p[4]={x1[1],x1[2],x1[3],r1};
        const float x2m[4]={l2,x2[0],x2[1],x2[2]}, x2p[4]={x2[1],x2[2],x2[3],r2};
        #pragma unroll
        for (int c = 0; c < 4; ++c) {
            const float r  = rr[c] + ggx[c]*uu0[c] + ggy[c]*uu1[c];
            const float ng = ggx[c]*ggx[c] + ggy[c]*ggy[c] + TVEPS;
            const float f  = (fabsf(r) < tl*ng) ? (r * fastrcp(ng)) : copysignf(tl, r);
            const float d1 = wx0*x1m[c] + wx1*x1[c] + wx2*x1p[c] + wy0*q1m[c] + wy1*q1c[c];
            const float d2 = wx0*x2m[c] + wx1*x2[c] + wx2*x2p[c] + wy0*q2m[c] + wy1*q2c[c];
            o0[c] = (uu0[c] - f*ggx[c]) + th0*d1;
            o1[c] = (uu1[c] - f*ggy[c]) + th0*d2;
        }
    };
    // fused u-step (interior rows)
    auto ustepF = [&](const float* q1m, const float* q1p, const float* q2m, const float* q2p) {
        float l1 = __shfl_up(p1x[3],1), l2 = __shfl_up(p2x[3],1);
        if (lane == 0) { l1 = 0.f; l2 = 0.f; }
        float r1 = __shfl_down(p1x[0],1), r2 = __shfl_down(p2x[0],1);
        if (lane == 63) { r1 = 0.f; r2 = 0.f; }
        const float x1m[4]={l1,p1x[0],p1x[1],p1x[2]}, x1p[4]={p1x[1],p1x[2],p1x[3],r1};
        const float x2m[4]={l2,p2x[0],p2x[1],p2x[2]}, x2p[4]={p2x[1],p2x[2],p2x[3],r2};
        #pragma unroll
        for (int c = 0; c < 4; ++c) {
            const float r  = rho[c] + gxr[c]*u0[c] + gyr[c]*u1[c];
            const float ng = gxr[c]*gxr[c] + gyr[c]*gyr[c] + TVEPS;
            const float f  = (fabsf(r) < tl*ng) ? (r * fastrcp(ng)) : copysignf(tl, r);
            const float d1 = wx0*x1m[c] + wx1*p1x[c] + wx2*x1p[c]
                           + wy0*q1m[c] + wy1*p1y[c] + wy2*q1p[c];
            const float d2 = wx0*x2m[c] + wx1*p2x[c] + wx2*x2p[c]
                           + wy0*q2m[c] + wy1*p2y[c] + wy2*q2p[c];
            u0[c] = (u0[c] - f*gxr[c]) + th0*d1;
            u1[c] = (u1[c] - f*gyr[c]) + th0*d2;
        }
    };

    for (int it = 0; it < NUM_ITER; ++it) {
        const bool last = (it == NUM_ITER-1);

        // ================= phase A: u-step =================
        if (wv == 0) {
            float pyp1[4], pyp2[4];
            LD4(pyp1, &xq1[1][x0]); LD4(pyp2, &xq2[1][x0]);
            float o0[4], o1[4];
            ustep_dym(rho, gxr, gyr, u0, u1, p1x, p1y, pyp1, p2x, p2y, pyp2, o0, o1);
            float hym1[4]={0,0,0,0}, hym2[4]={0,0,0,0};
            if (it > 0 && notTop) {
                int* fb = flags + (size_t)(it-1)*3*NBLK;
                if (lane == 0) waitflag(&fb[2*NBLK + (b-1)], FLAG_MAGIC | (it-1));
                const float* hp = halo + ((size_t)(it-1)*NBLK + (b-1))*HPLANES*W;
                #pragma unroll
                for (int c = 0; c < 4; ++c) {
                    hym1[c] = aload(hp + 6*W + x0 + c);
                    hym2[c] = aload(hp + 7*W + x0 + c);
                }
            }
            #pragma unroll
            for (int c = 0; c < 4; ++c) {
                u0[c] = o0[c] + th0*(wy0*hym1[c]);
                u1[c] = o1[c] + th0*(wy0*hym2[c]);
            }
        } else if (wv == 15) {
            float pym1[4], pym2[4];
            LD4(pym1, &xq1[14][x0]); LD4(pym2, &xq2[14][x0]);
            float o0[4], o1[4];
            ustep_dyp(rho, gxr, gyr, u0, u1, p1x, pym1, p1y, p2x, pym2, p2y, o0, o1);
            float hyp1[4]={0,0,0,0}, hyp2[4]={0,0,0,0};
            float cx1[4]={0,0,0,0}, cx2[4]={0,0,0,0};
            float cp1[4]={0,0,0,0}, cp2[4]={0,0,0,0};
            if (it > 0 && notBot) {
                int* fb = flags + (size_t)(it-1)*3*NBLK;
                const int nw = last ? 1 : 2;               // A always; B only if recompute
                if (lane < nw) waitflag(&fb[lane*NBLK + (b+1)], FLAG_MAGIC | (it-1));
                const float* hp = halo + ((size_t)(it-1)*NBLK + (b+1))*HPLANES*W;
                #pragma unroll
                for (int c = 0; c < 4; ++c) {
                    hyp1[c] = aload(hp + 1*W + x0 + c);    // p1y(16)
                    hyp2[c] = aload(hp + 3*W + x0 + c);    // p2y(16)
                }
                if (!last) {
                    #pragma unroll
                    for (int c = 0; c < 4; ++c) {
                        cx1[c] = aload(hp + 0*W + x0 + c); // p1x(16)
                        cx2[c] = aload(hp + 2*W + x0 + c); // p2x(16)
                        cp1[c] = aload(hp + 4*W + x0 + c); // p1y(17)
                        cp2[c] = aload(hp + 5*W + x0 + c); // p2y(17)
                    }
                }
            }
            #pragma unroll
            for (int c = 0; c < 4; ++c) {
                u0[c] = o0[c] + th0*(wy2*hyp1[c]);
                u1[c] = o1[c] + th0*(wy2*hyp2[c]);
            }
            if (!last) {
                ST4(&xu0[15][x0], u0); ST4(&xu1[15][x0], u1);
                if (notBot) {
                    // recompute u(16): bitwise mirror of b+1's wave-0 code path
                    float o160[4], o161[4];
                    ustep_dym(rho16, gx16, gy16, u16_0, u16_1,
                              cx1, hyp1, cp1, cx2, hyp2, cp2, o160, o161);
                    #pragma unroll
                    for (int c = 0; c < 4; ++c) {
                        u16_0[c] = o160[c] + th0*(wy0*p1y[c]);   // pre-p-step p1y(15)
                        u16_1[c] = o161[c] + th0*(wy0*p2y[c]);
                    }
                }
            }
        } else {
            float pym1[4], pym2[4], pyp1[4], pyp2[4];
            LD4(pym1, &xq1[wv-1][x0]); LD4(pym2, &xq2[wv-1][x0]);
            LD4(pyp1, &xq1[wv+1][x0]); LD4(pyp2, &xq2[wv+1][x0]);
            ustepF(pym1, pyp1, pym2, pyp2);
            ST4(&xu0[wv][x0], u0); ST4(&xu1[wv][x0], u1);
        }

        if (last) {
            float* __restrict__ o0 = uout + (size_t)(2*n)   * HW + (size_t)grow * W + x0;
            float* __restrict__ o1 = uout + (size_t)(2*n+1) * HW + (size_t)grow * W + x0;
            ST4(o0, u0); ST4(o1, u1);
            break;              // uniform across block
        }
        __syncthreads();   // barrier 1: xu rows 1..15 complete; prev-iter xq reads done

        // ================= phase B: p-step + publish =================
        float uy0[4], uy1[4];
        if (wv < 15)            { LD4(uy0, &xu0[wv+1][x0]); LD4(uy1, &xu1[wv+1][x0]); }
        else if (grow == H-1)   { for (int c=0;c<4;++c){ uy0[c]=0.f; uy1[c]=0.f; } }
        else                    { CP4(uy0, u16_0); CP4(uy1, u16_1); }
        float ur0 = __shfl_down(u0[0], 1), ur1 = __shfl_down(u1[0], 1);
        if (lane == 63) { ur0 = 0.f; ur1 = 0.f; }
        #pragma unroll
        for (int c = 0; c < 4; ++c) {
            const float uxp0 = (c < 3) ? u0[c+1] : ur0;
            const float uxp1 = (c < 3) ? u1[c+1] : ur1;
            const float g1x = uxp0 - u0[c];
            const float g1y = uy0[c] - u0[c];
            const float g2x = uxp1 - u1[c];
            const float g2y = uy1[c] - u1[c];
            const float rc1 = fastrcp(1.f + tt * (fabsf(g1x) + fabsf(g1y)));
            const float rc2 = fastrcp(1.f + tt * (fabsf(g2x) + fabsf(g2y)));
            p1x[c] = (p1x[c] + tt*g1x) * rc1;
            p1y[c] = (p1y[c] + tt*g1y) * rc1;
            p2x[c] = (p2x[c] + tt*g2x) * rc2;
            p2y[c] = (p2y[c] + tt*g2y) * rc2;
        }
        ST4(&xq1[wv][x0], p1y); ST4(&xq2[wv][x0], p2y);

        {
            float* hw = halo + ((size_t)it * NBLK + b) * HPLANES * W;
            int* fw = flags + (size_t)it * 3 * NBLK;
            const int ft = FLAG_MAGIC | it;
            if (wv == 0 && notTop) {
                #pragma unroll
                for (int c = 0; c < 4; ++c) {
                    astore(hw + 0*W + x0 + c, p1x[c]);
                    astore(hw + 1*W + x0 + c, p1y[c]);
                    astore(hw + 2*W + x0 + c, p2x[c]);
                    astore(hw + 3*W + x0 + c, p2y[c]);
                }
                if (lane == 0) setflag(&fw[0*NBLK + b], ft);   // A
            } else if (wv == 1 && notTop) {
                #pragma unroll
                for (int c = 0; c < 4; ++c) {
                    astore(hw + 4*W + x0 + c, p1y[c]);
                    astore(hw + 5*W + x0 + c, p2y[c]);
                }
                if (lane == 0) setflag(&fw[1*NBLK + b], ft);   // B
            } else if (wv == 15 && notBot) {
                #pragma unroll
                for (int c = 0; c < 4; ++c) {
                    astore(hw + 6*W + x0 + c, p1y[c]);
                    astore(hw + 7*W + x0 + c, p2y[c]);
                }
                if (lane == 0) setflag(&fw[2*NBLK + b], ft);   // C
            }
        }
        __syncthreads();   // barrier 2: xq writes visible for next iter's phase A
    }
}

// ---------------- fallback path (round-1, known good) ----------------

__global__ void precompute_kernel(const float* __restrict__ x,
                                  float* __restrict__ u,
                                  float* __restrict__ ws) {
    const int row = blockIdx.x;
    const int n = row / H, y = row % H;
    const int xx = threadIdx.x;
    const int idx = y * W + xx;
    const float* __restrict__ I0 = x + (size_t)n * HW;
    const float* __restrict__ I1 = x + (size_t)(NB + n) * HW;
    float* __restrict__ p1  = ws;
    float* __restrict__ p2  = ws + (size_t)2 * NB * HW;
    float* __restrict__ rho = ws + (size_t)4 * NB * HW;
    float* __restrict__ gxp = ws + (size_t)5 * NB * HW;
    float* __restrict__ gyp = ws + (size_t)6 * NB * HW;
    const float i1c = I1[idx];
    const bool xm = xx > 0, xp = xx < W - 1, ym = y > 0, yp = y < H - 1;
    float a00=0.f,a01=0.f,a02=0.f,a10=0.f,a12=0.f,a20=0.f,a21=0.f,a22=0.f;
    if (ym) { a01 = I1[idx-W]; if (xm) a00 = I1[idx-W-1]; if (xp) a02 = I1[idx-W+1]; }
    if (xm) a10 = I1[idx-1];
    if (xp) a12 = I1[idx+1];
    if (yp) { a21 = I1[idx+W]; if (xm) a20 = I1[idx+W-1]; if (xp) a22 = I1[idx+W+1]; }
    const float gxv = ((a02-a00) + 2.f*(a12-a10) + (a22-a20)) * (1.f/6.f);
    const float gyv = ((a20-a00) + 2.f*(a21-a01) + (a22-a02)) * (1.f/6.f);
    const size_t np = (size_t)n * HW;
    rho[np+idx] = i1c - I0[idx];
    gxp[np+idx] = gxv;
    gyp[np+idx] = gyv;
    u[(size_t)(2*n)*HW + idx] = 0.f;   u[(size_t)(2*n+1)*HW + idx] = 0.f;
    p1[(size_t)(2*n)*HW + idx] = 0.f;  p1[(size_t)(2*n+1)*HW + idx] = 0.f;
    p2[(size_t)(2*n)*HW + idx] = 0.f;  p2[(size_t)(2*n+1)*HW + idx] = 0.f;
}

__global__ void u_kernel(const float* __restrict__ ws,
                         float* __restrict__ u,
                         const float* __restrict__ lam,
                         const float* __restrict__ theta,
                         const float* __restrict__ wxv,
                         const float* __restrict__ wyv) {
    const int row = blockIdx.x;
    const int n = row / H, y = row % H;
    const int xx = threadIdx.x;
    const int idx = y * W + xx;
    const size_t np = (size_t)n * HW;
    const float* __restrict__ p1  = ws;
    const float* __restrict__ p2  = ws + (size_t)2 * NB * HW;
    const float* __restrict__ rho_c = ws + (size_t)4 * NB * HW;
    const float* __restrict__ gxp = ws + (size_t)5 * NB * HW;
    const float* __restrict__ gyp = ws + (size_t)6 * NB * HW;
    const float th0 = theta[0];
    const float tl = th0 * lam[0];
    const float wx0 = wxv[0], wx1 = wxv[1], wx2 = wxv[2];
    const float wy0 = wyv[0], wy1 = wyv[1], wy2 = wyv[2];
    const float gx = gxp[np+idx];
    const float gy = gyp[np+idx];
    float* __restrict__ u0p = u + (size_t)(2*n)*HW;
    float* __restrict__ u1p = u + (size_t)(2*n+1)*HW;
    const float u0 = u0p[idx], u1 = u1p[idx];
    const float rho = rho_c[np+idx] + gx*u0 + gy*u1;
    const float ng = gx*gx + gy*gy + TVEPS;
    const float th = tl * ng;
    float s0, s1;
    if (fabsf(rho) < th) { const float d = rho/ng; s0 = d*gx; s1 = d*gy; }
    else { const float sg = (rho > 0.f) ? 1.f : ((rho < 0.f) ? -1.f : 0.f);
           s0 = tl*gx*sg; s1 = tl*gy*sg; }
    const float v0 = u0 - s0, v1 = u1 - s1;
    const float* __restrict__ p1xp = p1 + (size_t)(2*n)*HW;
    const float* __restrict__ p1yp = p1 + (size_t)(2*n+1)*HW;
    const float* __restrict__ p2xp = p2 + (size_t)(2*n)*HW;
    const float* __restrict__ p2yp = p2 + (size_t)(2*n+1)*HW;
    float d1 = wx1*p1xp[idx] + wy1*p1yp[idx];
    float d2 = wx1*p2xp[idx] + wy1*p2yp[idx];
    if (xx > 0)     { d1 += wx0*p1xp[idx-1]; d2 += wx0*p2xp[idx-1]; }
    if (xx < W-1)   { d1 += wx2*p1xp[idx+1]; d2 += wx2*p2xp[idx+1]; }
    if (y > 0)      { d1 += wy0*p1yp[idx-W]; d2 += wy0*p2yp[idx-W]; }
    if (y < H-1)    { d1 += wy2*p1yp[idx+W]; d2 += wy2*p2yp[idx+W]; }
    u0p[idx] = v0 + th0*d1;
    u1p[idx] = v1 + th0*d2;
}

__global__ void p_kernel(const float* __restrict__ u,
                         float* __restrict__ ws,
                         const float* __restrict__ tau,
                         const float* __restrict__ theta) {
    const int row = blockIdx.x;
    const int n = row / H, y = row % H;
    const int xx = threadIdx.x;
    const int idx = y * W + xx;
    float* __restrict__ p1 = ws;
    float* __restrict__ p2 = ws + (size_t)2 * NB * HW;
    const float tt = tau[0] / theta[0];
    const float* __restrict__ u0p = u + (size_t)(2*n)*HW;
    const float* __restrict__ u1p = u + (size_t)(2*n+1)*HW;
    const float c0 = u0p[idx];
    const float g1x = ((xx < W-1) ? u0p[idx+1] : 0.f) - c0;
    const float g1y = ((y < H-1) ? u0p[idx+W] : 0.f) - c0;
    const float c1 = u1p[idx];
    const float g2x = ((xx < W-1) ? u1p[idx+1] : 0.f) - c1;
    const float g2y = ((y < H-1) ? u1p[idx+W] : 0.f) - c1;
    float* __restrict__ p1xp = p1 + (size_t)(2*n)*HW;
    float* __restrict__ p1yp = p1 + (size_t)(2*n+1)*HW;
    float* __restrict__ p2xp = p2 + (size_t)(2*n)*HW;
    float* __restrict__ p2yp = p2 + (size_t)(2*n+1)*HW;
    const float den1 = 1.f + tt * (fabsf(g1x) + fabsf(g1y));
    p1xp[idx] = (p1xp[idx] + tt*g1x) / den1;
    p1yp[idx] = (p1yp[idx] + tt*g1y) / den1;
    const float den2 = 1.f + tt * (fabsf(g2x) + fabsf(g2y));
    p2xp[idx] = (p2xp[idx] + tt*g2x) / den2;
    p2yp[idx] = (p2yp[idx] + tt*g2y) / den2;
}

extern "C" void kernel_launch(void* const* d_in, const int* in_sizes, int n_in,
                              void* d_out, int out_size, void* d_ws, size_t ws_size,
                              hipStream_t stream) {
    const float* x     = (const float*)d_in[0];
    const float* lam   = (const float*)d_in[1];
    const float* tau   = (const float*)d_in[2];
    const float* theta = (const float*)d_in[3];
    const float* wxv   = (const float*)d_in[4];
    const float* wyv   = (const float*)d_in[5];
    float* u = (float*)d_out;

    const size_t halo_floats = (size_t)(NUM_ITER-1) * NBLK * HPLANES * W;
    const size_t need = halo_floats * sizeof(float)
                      + (size_t)(NUM_ITER-1) * 3 * NBLK * sizeof(int);

    if (ws_size >= need) {
        float* halo = (float*)d_ws;
        int* flags = (int*)((char*)d_ws + halo_floats * sizeof(float));
        void* args[] = { (void*)&x, (void*)&lam, (void*)&tau, (void*)&theta,
                         (void*)&wxv, (void*)&wyv, (void*)&u, (void*)&halo, (void*)&flags };
        hipLaunchCooperativeKernel((void*)tvl1_dfr_kernel, dim3(NBLK), dim3(NTHREADS),
                                   args, 0, stream);
    } else {
        float* ws = (float*)d_ws;
        const dim3 grid(NB * H);
        const dim3 block(W);
        precompute_kernel<<<grid, block, 0, stream>>>(x, u, ws);
        for (int it = 0; it < NUM_ITER; ++it) {
            u_kernel<<<grid, block, 0, stream>>>(ws, u, lam, theta, wxv, wyv);
            p_kernel<<<grid, block, 0, stream>>>(u, ws, tau, theta);
        }
    }
}

// Round 11
// 111.325 us; speedup vs baseline: 1.6041x; 1.1076x over previous
//
#include <hip/hip_runtime.h>

#define W 256
#define H 256
#define HW (W*H)
#define NB 12
#define ROWS 16
#define BPI (H/ROWS)            // 16 strips per image
#define NBLK (NB*BPI)           // 192 blocks (1/CU, co-resident via cooperative launch)
#define NTHREADS 1024           // 16 waves; wave = row, lane = 4-px chunk
#define NUM_ITER 20
#define TVEPS 1e-8f
#define HPLANES 8
#define FLAG_MAGIC 0x5A170000

// d_ws layout: halo[NUM_ITER-1][NBLK][HPLANES][W] floats, then flags[NUM_ITER-1][3][NBLK].
// planes: 0:p1x(r0) 1:p1y(r0) 2:p2x(r0) 3:p2y(r0) 4:p1y(r1) 5:p2y(r1) 6:p1y(r15) 7:p2y(r15)
// flags : 0=A (wave0, planes0-3) 1=B (wave1, planes4-5) 2=C (wave15, planes6-7)
// R7 structure; consumer waves compute BEFORE polling (halo term deferred for waves 0/15,
// pure code motion for wave 14) so the IC observe latency hides under own compute.

__device__ __forceinline__ float aload(const float* p) {
    return __hip_atomic_load(p, __ATOMIC_RELAXED, __HIP_MEMORY_SCOPE_AGENT);
}
__device__ __forceinline__ void astore(float* p, float v) {
    __hip_atomic_store(p, v, __ATOMIC_RELAXED, __HIP_MEMORY_SCOPE_AGENT);
}
__device__ __forceinline__ void waitflag(const int* f, int tgt) {
    while (__hip_atomic_load(f, __ATOMIC_RELAXED, __HIP_MEMORY_SCOPE_AGENT) != tgt)
        __builtin_amdgcn_s_sleep(1);
    asm volatile("" ::: "memory");
}
__device__ __forceinline__ void setflag(int* f, int tgt) {
    asm volatile("s_waitcnt vmcnt(0)" ::: "memory");
    __hip_atomic_store(f, tgt, __ATOMIC_RELAXED, __HIP_MEMORY_SCOPE_AGENT);
}
__device__ __forceinline__ float fastrcp(float x) { return __builtin_amdgcn_rcpf(x); }

#define LD4(dst, ptr) { const float4 _t = *reinterpret_cast<const float4*>(ptr); \
                        dst[0]=_t.x; dst[1]=_t.y; dst[2]=_t.z; dst[3]=_t.w; }
#define ST4(ptr, src) { float4 _t; _t.x=src[0]; _t.y=src[1]; _t.z=src[2]; _t.w=src[3]; \
                        *reinterpret_cast<float4*>(ptr) = _t; }

__global__ __launch_bounds__(NTHREADS, 1) void tvl1_ovl_kernel(
    const float* __restrict__ xin,
    const float* __restrict__ lam,
    const float* __restrict__ tau,
    const float* __restrict__ theta,
    const float* __restrict__ wxv,
    const float* __restrict__ wyv,
    float* __restrict__ uout,
    float* __restrict__ halo,
    int* __restrict__ flags)
{
    __shared__ float xu0[ROWS+1][W];   // u rows 0..16 (row16 maintained by wave 14)
    __shared__ float xu1[ROWS+1][W];
    __shared__ float xq1[ROWS][W];     // p1y rows 0..15
    __shared__ float xq2[ROWS][W];

    const int tid  = threadIdx.x;
    const int lane = tid & 63;
    const int wv   = tid >> 6;          // row within strip, 0..15
    const int x0   = lane << 2;
    const int b    = blockIdx.x;
    const int n    = b / BPI, bi = b % BPI;
    const int r0   = bi * ROWS;
    const int grow = r0 + wv;
    const bool notTop = (bi > 0), notBot = (bi < BPI-1);

    const float th0 = theta[0];
    const float tl  = th0 * lam[0];
    const float tt  = tau[0] / th0;
    const float wx0 = wxv[0], wx1 = wxv[1], wx2 = wxv[2];
    const float wy0 = wyv[0], wy1 = wyv[1], wy2 = wyv[2];

    const float* __restrict__ I0 = xin + (size_t)n * HW;
    const float* __restrict__ I1 = xin + (size_t)(NB + n) * HW;

    auto grad4 = [&](int row, float* rr, float* ggx, float* ggy) {
        #pragma unroll
        for (int c = 0; c < 4; ++c) {
            const int xc = x0 + c;
            const int idx = row * W + xc;
            const bool xm = xc > 0, xp = xc < W-1, ym = row > 0, yp = row < H-1;
            float a00=0.f,a01=0.f,a02=0.f,a10=0.f,a12=0.f,a20=0.f,a21=0.f,a22=0.f;
            if (ym) { a01=I1[idx-W]; if (xm) a00=I1[idx-W-1]; if (xp) a02=I1[idx-W+1]; }
            if (xm) a10=I1[idx-1];
            if (xp) a12=I1[idx+1];
            if (yp) { a21=I1[idx+W]; if (xm) a20=I1[idx+W-1]; if (xp) a22=I1[idx+W+1]; }
            ggx[c] = ((a02-a00) + 2.f*(a12-a10) + (a22-a20)) * (1.f/6.f);
            ggy[c] = ((a20-a00) + 2.f*(a21-a01) + (a22-a02)) * (1.f/6.f);
            rr[c]  = I1[idx] - I0[idx];
        }
    };

    float rho[4], gxr[4], gyr[4];
    grad4(grow, rho, gxr, gyr);
    float rho16[4]={0,0,0,0}, gx16[4]={0,0,0,0}, gy16[4]={0,0,0,0};
    if (wv == 14 && notBot) grad4(r0 + ROWS, rho16, gx16, gy16);   // halo grads in regs

    for (int k = tid; k < (ROWS+1)*W; k += NTHREADS) { (&xu0[0][0])[k]=0.f; (&xu1[0][0])[k]=0.f; }
    for (int k = tid; k < ROWS*W;     k += NTHREADS) { (&xq1[0][0])[k]=0.f; (&xq2[0][0])[k]=0.f; }
    float u0[4]={0,0,0,0}, u1[4]={0,0,0,0};
    float p1x[4]={0,0,0,0}, p1y[4]={0,0,0,0}, p2x[4]={0,0,0,0}, p2y[4]={0,0,0,0};
    __syncthreads();

    // u-step with ym term DEFERRED: caller adds th0*(wy0*q1m) afterwards.
    // Used by wave 0 (own row) AND wave 14 (halo row-16 recompute) -> bitwise match.
    auto ustep_dym = [&](const float* rr, const float* ggx, const float* ggy,
                         const float* uu0, const float* uu1,
                         const float* x1, const float* q1c, const float* q1p,
                         const float* x2, const float* q2c, const float* q2p,
                         float* o0, float* o1) {
        float l1 = __shfl_up(x1[3],1), l2 = __shfl_up(x2[3],1);
        if (lane == 0) { l1 = 0.f; l2 = 0.f; }
        float r1 = __shfl_down(x1[0],1), r2 = __shfl_down(x2[0],1);
        if (lane == 63) { r1 = 0.f; r2 = 0.f; }
        const float x1m[4]={l1,x1[0],x1[1],x1[2]}, x1p[4]={x1[1],x1[2],x1[3],r1};
        const float x2m[4]={l2,x2[0],x2[1],x2[2]}, x2p[4]={x2[1],x2[2],x2[3],r2};
        #pragma unroll
        for (int c = 0; c < 4; ++c) {
            const float r  = rr[c] + ggx[c]*uu0[c] + ggy[c]*uu1[c];
            const float ng = ggx[c]*ggx[c] + ggy[c]*ggy[c] + TVEPS;
            const float f  = (fabsf(r) < tl*ng) ? (r * fastrcp(ng)) : copysignf(tl, r);
            const float d1 = wx0*x1m[c] + wx1*x1[c] + wx2*x1p[c] + wy1*q1c[c] + wy2*q1p[c];
            const float d2 = wx0*x2m[c] + wx1*x2[c] + wx2*x2p[c] + wy1*q2c[c] + wy2*q2p[c];
            o0[c] = (uu0[c] - f*ggx[c]) + th0*d1;
            o1[c] = (uu1[c] - f*ggy[c]) + th0*d2;
        }
    };
    // u-step with yp term DEFERRED: caller adds th0*(wy2*q1p) afterwards (wave 15 own row)
    auto ustep_dyp = [&](const float* rr, const float* ggx, const float* ggy,
                         const float* uu0, const float* uu1,
                         const float* x1, const float* q1m, const float* q1c,
                         const float* x2, const float* q2m, const float* q2c,
                         float* o0, float* o1) {
        float l1 = __shfl_up(x1[3],1), l2 = __shfl_up(x2[3],1);
        if (lane == 0) { l1 = 0.f; l2 = 0.f; }
        float r1 = __shfl_down(x1[0],1), r2 = __shfl_down(x2[0],1);
        if (lane == 63) { r1 = 0.f; r2 = 0.f; }
        const float x1m[4]={l1,x1[0],x1[1],x1[2]}, x1p[4]={x1[1],x1[2],x1[3],r1};
        const float x2m[4]={l2,x2[0],x2[1],x2[2]}, x2p[4]={x2[1],x2[2],x2[3],r2};
        #pragma unroll
        for (int c = 0; c < 4; ++c) {
            const float r  = rr[c] + ggx[c]*uu0[c] + ggy[c]*uu1[c];
            const float ng = ggx[c]*ggx[c] + ggy[c]*ggy[c] + TVEPS;
            const float f  = (fabsf(r) < tl*ng) ? (r * fastrcp(ng)) : copysignf(tl, r);
            const float d1 = wx0*x1m[c] + wx1*x1[c] + wx2*x1p[c] + wy0*q1m[c] + wy1*q1c[c];
            const float d2 = wx0*x2m[c] + wx1*x2[c] + wx2*x2p[c] + wy0*q2m[c] + wy1*q2c[c];
            o0[c] = (uu0[c] - f*ggx[c]) + th0*d1;
            o1[c] = (uu1[c] - f*ggy[c]) + th0*d2;
        }
    };
    // fused u-step (interior rows 1..14)
    auto ustepF = [&](const float* q1m, const float* q1p, const float* q2m, const float* q2p) {
        float l1 = __shfl_up(p1x[3],1), l2 = __shfl_up(p2x[3],1);
        if (lane == 0) { l1 = 0.f; l2 = 0.f; }
        float r1 = __shfl_down(p1x[0],1), r2 = __shfl_down(p2x[0],1);
        if (lane == 63) { r1 = 0.f; r2 = 0.f; }
        const float x1m[4]={l1,p1x[0],p1x[1],p1x[2]}, x1p[4]={p1x[1],p1x[2],p1x[3],r1};
        const float x2m[4]={l2,p2x[0],p2x[1],p2x[2]}, x2p[4]={p2x[1],p2x[2],p2x[3],r2};
        #pragma unroll
        for (int c = 0; c < 4; ++c) {
            const float r  = rho[c] + gxr[c]*u0[c] + gyr[c]*u1[c];
            const float ng = gxr[c]*gxr[c] + gyr[c]*gyr[c] + TVEPS;
            const float f  = (fabsf(r) < tl*ng) ? (r * fastrcp(ng)) : copysignf(tl, r);
            const float d1 = wx0*x1m[c] + wx1*p1x[c] + wx2*x1p[c]
                           + wy0*q1m[c] + wy1*p1y[c] + wy2*q1p[c];
            const float d2 = wx0*x2m[c] + wx1*p2x[c] + wx2*x2p[c]
                           + wy0*q2m[c] + wy1*p2y[c] + wy2*q2p[c];
            u0[c] = (u0[c] - f*gxr[c]) + th0*d1;
            u1[c] = (u1[c] - f*gyr[c]) + th0*d2;
        }
    };

    for (int it = 0; it < NUM_ITER; ++it) {
        const bool last = (it == NUM_ITER-1);

        // ================= phase A: u-step (compute first, poll late) =================
        if (wv == 0) {
            float pyp1[4], pyp2[4];
            LD4(pyp1, &xq1[1][x0]); LD4(pyp2, &xq2[1][x0]);
            float o0[4], o1[4];
            ustep_dym(rho, gxr, gyr, u0, u1, p1x, p1y, pyp1, p2x, p2y, pyp2, o0, o1);
            float hym1[4]={0,0,0,0}, hym2[4]={0,0,0,0};
            if (it > 0 && notTop) {
                if (lane == 0) waitflag(&flags[(size_t)(it-1)*3*NBLK + 2*NBLK + (b-1)],
                                        FLAG_MAGIC | (it-1));                   // C(b-1)
                const float* hp = halo + ((size_t)(it-1)*NBLK + (b-1))*HPLANES*W;
                #pragma unroll
                for (int c = 0; c < 4; ++c) {
                    hym1[c] = aload(hp + 6*W + x0 + c);
                    hym2[c] = aload(hp + 7*W + x0 + c);
                }
            }
            #pragma unroll
            for (int c = 0; c < 4; ++c) {
                u0[c] = o0[c] + th0*(wy0*hym1[c]);
                u1[c] = o1[c] + th0*(wy0*hym2[c]);
            }
        } else if (wv == ROWS-1) {
            float pym1[4], pym2[4];
            LD4(pym1, &xq1[ROWS-2][x0]); LD4(pym2, &xq2[ROWS-2][x0]);
            float o0[4], o1[4];
            ustep_dyp(rho, gxr, gyr, u0, u1, p1x, pym1, p1y, p2x, pym2, p2y, o0, o1);
            float hyp1[4]={0,0,0,0}, hyp2[4]={0,0,0,0};
            if (it > 0 && notBot) {
                if (lane == 0) waitflag(&flags[(size_t)(it-1)*3*NBLK + 0*NBLK + (b+1)],
                                        FLAG_MAGIC | (it-1));                   // A(b+1)
                const float* hp = halo + ((size_t)(it-1)*NBLK + (b+1))*HPLANES*W;
                #pragma unroll
                for (int c = 0; c < 4; ++c) {
                    hyp1[c] = aload(hp + 1*W + x0 + c);    // p1y(16)
                    hyp2[c] = aload(hp + 3*W + x0 + c);    // p2y(16)
                }
            }
            #pragma unroll
            for (int c = 0; c < 4; ++c) {
                u0[c] = o0[c] + th0*(wy2*hyp1[c]);
                u1[c] = o1[c] + th0*(wy2*hyp2[c]);
            }
        } else {
            float pym1[4], pym2[4], pyp1[4], pyp2[4];
            LD4(pym1, &xq1[wv-1][x0]); LD4(pym2, &xq2[wv-1][x0]);
            LD4(pyp1, &xq1[wv+1][x0]); LD4(pyp2, &xq2[wv+1][x0]);
            ustepF(pym1, pyp1, pym2, pyp2);
        }

        if (last) {
            float* __restrict__ o0 = uout + (size_t)(2*n)   * HW + (size_t)grow * W + x0;
            float* __restrict__ o1 = uout + (size_t)(2*n+1) * HW + (size_t)grow * W + x0;
            ST4(o0, u0); ST4(o1, u1);
            break;              // uniform across block
        }
        ST4(&xu0[wv][x0], u0); ST4(&xu1[wv][x0], u1);

        // ---- wave 14: poll AFTER own u-step; halo row-16 recompute via deferred path ----
        if (wv == 14 && notBot) {
            float c16x1[4]={0,0,0,0}, c16x2[4]={0,0,0,0};
            float c16c1[4]={0,0,0,0}, c16c2[4]={0,0,0,0};
            float c16p1[4]={0,0,0,0}, c16p2[4]={0,0,0,0};
            if (it > 0) {
                int* fb = flags + (size_t)(it-1)*3*NBLK;
                if (lane < 2) waitflag(&fb[lane*NBLK + (b+1)], FLAG_MAGIC | (it-1)); // A,B(b+1)
                const float* hp = halo + ((size_t)(it-1)*NBLK + (b+1))*HPLANES*W;
                #pragma unroll
                for (int c = 0; c < 4; ++c) {
                    c16x1[c] = aload(hp + 0*W + x0 + c);   // p1x(16)
                    c16c1[c] = aload(hp + 1*W + x0 + c);   // p1y(16)
                    c16x2[c] = aload(hp + 2*W + x0 + c);   // p2x(16)
                    c16c2[c] = aload(hp + 3*W + x0 + c);   // p2y(16)
                    c16p1[c] = aload(hp + 4*W + x0 + c);   // p1y(17)
                    c16p2[c] = aload(hp + 5*W + x0 + c);   // p2y(17)
                }
            }
            float q115[4], q215[4], u160[4], u161[4];
            LD4(q115, &xq1[ROWS-1][x0]); LD4(q215, &xq2[ROWS-1][x0]);  // prev-iter p1y/p2y(15)
            LD4(u160, &xu0[ROWS][x0]);   LD4(u161, &xu1[ROWS][x0]);    // self-maintained u(16)
            float n160[4], n161[4];
            ustep_dym(rho16, gx16, gy16, u160, u161,
                      c16x1, c16c1, c16p1, c16x2, c16c2, c16p2, n160, n161);
            #pragma unroll
            for (int c = 0; c < 4; ++c) {
                n160[c] += th0*(wy0*q115[c]);   // same late-add order as neighbor's wave 0
                n161[c] += th0*(wy0*q215[c]);
            }
            ST4(&xu0[ROWS][x0], n160); ST4(&xu1[ROWS][x0], n161);
        }
        __syncthreads();   // barrier 1: xu (incl. row 16) complete; prev-iter xq reads done

        // ================= phase B: p-step + publish (identical to R7) =================
        float uy0[4], uy1[4];
        if (grow == H-1) { for (int c=0;c<4;++c){ uy0[c]=0.f; uy1[c]=0.f; } }
        else             { LD4(uy0, &xu0[wv+1][x0]); LD4(uy1, &xu1[wv+1][x0]); }
        float ur0 = __shfl_down(u0[0], 1), ur1 = __shfl_down(u1[0], 1);
        if (lane == 63) { ur0 = 0.f; ur1 = 0.f; }
        #pragma unroll
        for (int c = 0; c < 4; ++c) {
            const float uxp0 = (c < 3) ? u0[c+1] : ur0;
            const float uxp1 = (c < 3) ? u1[c+1] : ur1;
            const float g1x = uxp0 - u0[c];
            const float g1y = uy0[c] - u0[c];
            const float g2x = uxp1 - u1[c];
            const float g2y = uy1[c] - u1[c];
            const float rc1 = fastrcp(1.f + tt * (fabsf(g1x) + fabsf(g1y)));
            const float rc2 = fastrcp(1.f + tt * (fabsf(g2x) + fabsf(g2y)));
            p1x[c] = (p1x[c] + tt*g1x) * rc1;
            p1y[c] = (p1y[c] + tt*g1y) * rc1;
            p2x[c] = (p2x[c] + tt*g2x) * rc2;
            p2y[c] = (p2y[c] + tt*g2y) * rc2;
        }
        ST4(&xq1[wv][x0], p1y); ST4(&xq2[wv][x0], p2y);

        {
            float* hw = halo + ((size_t)it * NBLK + b) * HPLANES * W;
            int* fw = flags + (size_t)it * 3 * NBLK;
            const int ft = FLAG_MAGIC | it;
            if (wv == 0 && notTop) {
                #pragma unroll
                for (int c = 0; c < 4; ++c) {
                    astore(hw + 0*W + x0 + c, p1x[c]);
                    astore(hw + 1*W + x0 + c, p1y[c]);
                    astore(hw + 2*W + x0 + c, p2x[c]);
                    astore(hw + 3*W + x0 + c, p2y[c]);
                }
                if (lane == 0) setflag(&fw[0*NBLK + b], ft);   // A
            } else if (wv == 1 && notTop) {
                #pragma unroll
                for (int c = 0; c < 4; ++c) {
                    astore(hw + 4*W + x0 + c, p1y[c]);
                    astore(hw + 5*W + x0 + c, p2y[c]);
                }
                if (lane == 0) setflag(&fw[1*NBLK + b], ft);   // B
            } else if (wv == ROWS-1 && notBot) {
                #pragma unroll
                for (int c = 0; c < 4; ++c) {
                    astore(hw + 6*W + x0 + c, p1y[c]);
                    astore(hw + 7*W + x0 + c, p2y[c]);
                }
                if (lane == 0) setflag(&fw[2*NBLK + b], ft);   // C
            }
        }
        __syncthreads();   // barrier 2: xq writes visible for next iter's phase A
    }
}

// ---------------- fallback path (round-1, known good) ----------------

__global__ void precompute_kernel(const float* __restrict__ x,
                                  float* __restrict__ u,
                                  float* __restrict__ ws) {
    const int row = blockIdx.x;
    const int n = row / H, y = row % H;
    const int xx = threadIdx.x;
    const int idx = y * W + xx;
    const float* __restrict__ I0 = x + (size_t)n * HW;
    const float* __restrict__ I1 = x + (size_t)(NB + n) * HW;
    float* __restrict__ p1  = ws;
    float* __restrict__ p2  = ws + (size_t)2 * NB * HW;
    float* __restrict__ rho = ws + (size_t)4 * NB * HW;
    float* __restrict__ gxp = ws + (size_t)5 * NB * HW;
    float* __restrict__ gyp = ws + (size_t)6 * NB * HW;
    const float i1c = I1[idx];
    const bool xm = xx > 0, xp = xx < W - 1, ym = y > 0, yp = y < H - 1;
    float a00=0.f,a01=0.f,a02=0.f,a10=0.f,a12=0.f,a20=0.f,a21=0.f,a22=0.f;
    if (ym) { a01 = I1[idx-W]; if (xm) a00 = I1[idx-W-1]; if (xp) a02 = I1[idx-W+1]; }
    if (xm) a10 = I1[idx-1];
    if (xp) a12 = I1[idx+1];
    if (yp) { a21 = I1[idx+W]; if (xm) a20 = I1[idx+W-1]; if (xp) a22 = I1[idx+W+1]; }
    const float gxv = ((a02-a00) + 2.f*(a12-a10) + (a22-a20)) * (1.f/6.f);
    const float gyv = ((a20-a00) + 2.f*(a21-a01) + (a22-a02)) * (1.f/6.f);
    const size_t np = (size_t)n * HW;
    rho[np+idx] = i1c - I0[idx];
    gxp[np+idx] = gxv;
    gyp[np+idx] = gyv;
    u[(size_t)(2*n)*HW + idx] = 0.f;   u[(size_t)(2*n+1)*HW + idx] = 0.f;
    p1[(size_t)(2*n)*HW + idx] = 0.f;  p1[(size_t)(2*n+1)*HW + idx] = 0.f;
    p2[(size_t)(2*n)*HW + idx] = 0.f;  p2[(size_t)(2*n+1)*HW + idx] = 0.f;
}

__global__ void u_kernel(const float* __restrict__ ws,
                         float* __restrict__ u,
                         const float* __restrict__ lam,
                         const float* __restrict__ theta,
                         const float* __restrict__ wxv,
                         const float* __restrict__ wyv) {
    const int row = blockIdx.x;
    const int n = row / H, y = row % H;
    const int xx = threadIdx.x;
    const int idx = y * W + xx;
    const size_t np = (size_t)n * HW;
    const float* __restrict__ p1  = ws;
    const float* __restrict__ p2  = ws + (size_t)2 * NB * HW;
    const float* __restrict__ rho_c = ws + (size_t)4 * NB * HW;
    const float* __restrict__ gxp = ws + (size_t)5 * NB * HW;
    const float* __restrict__ gyp = ws + (size_t)6 * NB * HW;
    const float th0 = theta[0];
    const float tl = th0 * lam[0];
    const float wx0 = wxv[0], wx1 = wxv[1], wx2 = wxv[2];
    const float wy0 = wyv[0], wy1 = wyv[1], wy2 = wyv[2];
    const float gx = gxp[np+idx];
    const float gy = gyp[np+idx];
    float* __restrict__ u0p = u + (size_t)(2*n)*HW;
    float* __restrict__ u1p = u + (size_t)(2*n+1)*HW;
    const float u0 = u0p[idx], u1 = u1p[idx];
    const float rho = rho_c[np+idx] + gx*u0 + gy*u1;
    const float ng = gx*gx + gy*gy + TVEPS;
    const float th = tl * ng;
    float s0, s1;
    if (fabsf(rho) < th) { const float d = rho/ng; s0 = d*gx; s1 = d*gy; }
    else { const float sg = (rho > 0.f) ? 1.f : ((rho < 0.f) ? -1.f : 0.f);
           s0 = tl*gx*sg; s1 = tl*gy*sg; }
    const float v0 = u0 - s0, v1 = u1 - s1;
    const float* __restrict__ p1xp = p1 + (size_t)(2*n)*HW;
    const float* __restrict__ p1yp = p1 + (size_t)(2*n+1)*HW;
    const float* __restrict__ p2xp = p2 + (size_t)(2*n)*HW;
    const float* __restrict__ p2yp = p2 + (size_t)(2*n+1)*HW;
    float d1 = wx1*p1xp[idx] + wy1*p1yp[idx];
    float d2 = wx1*p2xp[idx] + wy1*p2yp[idx];
    if (xx > 0)     { d1 += wx0*p1xp[idx-1]; d2 += wx0*p2xp[idx-1]; }
    if (xx < W-1)   { d1 += wx2*p1xp[idx+1]; d2 += wx2*p2xp[idx+1]; }
    if (y > 0)      { d1 += wy0*p1yp[idx-W]; d2 += wy0*p2yp[idx-W]; }
    if (y < H-1)    { d1 += wy2*p1yp[idx+W]; d2 += wy2*p2yp[idx+W]; }
    u0p[idx] = v0 + th0*d1;
    u1p[idx] = v1 + th0*d2;
}

__global__ void p_kernel(const float* __restrict__ u,
                         float* __restrict__ ws,
                         const float* __restrict__ tau,
                         const float* __restrict__ theta) {
    const int row = blockIdx.x;
    const int n = row / H, y = row % H;
    const int xx = threadIdx.x;
    const int idx = y * W + xx;
    float* __restrict__ p1 = ws;
    float* __restrict__ p2 = ws + (size_t)2 * NB * HW;
    const float tt = tau[0] / theta[0];
    const float* __restrict__ u0p = u + (size_t)(2*n)*HW;
    const float* __restrict__ u1p = u + (size_t)(2*n+1)*HW;
    const float c0 = u0p[idx];
    const float g1x = ((xx < W-1) ? u0p[idx+1] : 0.f) - c0;
    const float g1y = ((y < H-1) ? u0p[idx+W] : 0.f) - c0;
    const float c1 = u1p[idx];
    const float g2x = ((xx < W-1) ? u1p[idx+1] : 0.f) - c1;
    const float g2y = ((y < H-1) ? u1p[idx+W] : 0.f) - c1;
    float* __restrict__ p1xp = p1 + (size_t)(2*n)*HW;
    float* __restrict__ p1yp = p1 + (size_t)(2*n+1)*HW;
    float* __restrict__ p2xp = p2 + (size_t)(2*n)*HW;
    float* __restrict__ p2yp = p2 + (size_t)(2*n+1)*HW;
    const float den1 = 1.f + tt * (fabsf(g1x) + fabsf(g1y));
    p1xp[idx] = (p1xp[idx] + tt*g1x) / den1;
    p1yp[idx] = (p1yp[idx] + tt*g1y) / den1;
    const float den2 = 1.f + tt * (fabsf(g2x) + fabsf(g2y));
    p2xp[idx] = (p2xp[idx] + tt*g2x) / den2;
    p2yp[idx] = (p2yp[idx] + tt*g2y) / den2;
}

extern "C" void kernel_launch(void* const* d_in, const int* in_sizes, int n_in,
                              void* d_out, int out_size, void* d_ws, size_t ws_size,
                              hipStream_t stream) {
    const float* x     = (const float*)d_in[0];
    const float* lam   = (const float*)d_in[1];
    const float* tau   = (const float*)d_in[2];
    const float* theta = (const float*)d_in[3];
    const float* wxv   = (const float*)d_in[4];
    const float* wyv   = (const float*)d_in[5];
    float* u = (float*)d_out;

    const size_t halo_floats = (size_t)(NUM_ITER-1) * NBLK * HPLANES * W;
    const size_t need = halo_floats * sizeof(float)
                      + (size_t)(NUM_ITER-1) * 3 * NBLK * sizeof(int);

    if (ws_size >= need) {
        float* halo = (float*)d_ws;
        int* flags = (int*)((char*)d_ws + halo_floats * sizeof(float));
        void* args[] = { (void*)&x, (void*)&lam, (void*)&tau, (void*)&theta,
                         (void*)&wxv, (void*)&wyv, (void*)&u, (void*)&halo, (void*)&flags };
        hipLaunchCooperativeKernel((void*)tvl1_ovl_kernel, dim3(NBLK), dim3(NTHREADS),
                                   args, 0, stream);
    } else {
        float* ws = (float*)d_ws;
        const dim3 grid(NB * H);
        const dim3 block(W);
        precompute_kernel<<<grid, block, 0, stream>>>(x, u, ws);
        for (int it = 0; it < NUM_ITER; ++it) {
            u_kernel<<<grid, block, 0, stream>>>(ws, u, lam, theta, wxv, wyv);
            p_kernel<<<grid, block, 0, stream>>>(u, ws, tau, theta);
        }
    }
}